// Round 2
// baseline (251.392 us; speedup 1.0000x reference)
//
#include <hip/hip_runtime.h>
#include <math.h>

#define IMG 512
#define NB 8
#define TILE 32
#define GD 36            // TILE + 4 halo
#define NCH 9            // silu + 8 bases
#define NCONV 16

// ws layout (floats): [0,225) = Wc composed 5x5x9 kernel, [256, 256+1296) = W1
#define WOFF_WC 0
#define WOFF_W1 256

typedef float f4 __attribute__((ext_vector_type(4)));

// ---- closed-form cubic B-spline bases on uniform grid t_j=(j-3)*0.4-1 + silu
// u = x*2.5 + 5.5 maps knots to integers; interval i=floor(u), local t=u-i.
// Nonzero bases: j=i-3..i with standard uniform cubic weights.
__device__ __forceinline__ void eval_g(float xv, float& sl, f4& v0, f4& v1) {
    float u = fmaf(xv, 2.5f, 5.5f);
    float fi = floorf(u);
    int i = (int)fi;
    float t = u - fi;
    float s1 = 1.f - t;
    float t2 = t * t, t3 = t2 * t;
    float w0 = s1 * s1 * s1 * (1.f / 6.f);
    float w3 = t3 * (1.f / 6.f);
    float w1v = fmaf(0.5f, t3, 2.f / 3.f) - t2;          // (3t^3-6t^2+4)/6
    float msk = (u >= 0.f && u < 11.f) ? 1.f : 0.f;      // outside grid -> all bases 0
    w0 *= msk; w1v *= msk; w3 *= msk;
    float w2v = msk - w0 - w1v - w3;                     // partition of unity
    float bj[8];
#pragma unroll
    for (int j = 0; j < 8; ++j) {
        float v = 0.f;
        v = (i == j)     ? w3  : v;
        v = (i == j + 1) ? w2v : v;
        v = (i == j + 2) ? w1v : v;
        v = (i == j + 3) ? w0  : v;
        bj[j] = v;
    }
    v0 = f4{bj[0], bj[1], bj[2], bj[3]};
    v1 = f4{bj[4], bj[5], bj[6], bj[7]};
    sl = xv / (1.f + __expf(-xv));
}

// ---- prep: W1 (KAN weights over g-channels) and composed 5x5x9 kernel Wc
__global__ void ConvKAN_prep(const float* __restrict__ bw, const float* __restrict__ sw,
                             const float* __restrict__ ss, const float* __restrict__ rw,
                             float* __restrict__ ws) {
    int t = threadIdx.x;
    for (int idx = t; idx < NCONV * 9 * NCH; idx += 256) {
        int ci = idx / NCH;
        int ch = idx % NCH;
        ws[WOFF_W1 + idx] = (ch == 0) ? bw[ci] : sw[ci * 8 + (ch - 1)] * ss[ci];
    }
    for (int idx = t; idx < 25 * NCH; idx += 256) {
        int de = idx / NCH, ch = idx % NCH;
        int d = de / 5, e = de % 5;
        float s = 0.0f;
        for (int c = 0; c < NCONV; ++c) {
            int ulo = d - 2 > 0 ? d - 2 : 0, uhi = d < 2 ? d : 2;
            int vlo = e - 2 > 0 ? e - 2 : 0, vhi = e < 2 ? e : 2;
            for (int u = ulo; u <= uhi; ++u)
                for (int v = vlo; v <= vhi; ++v) {
                    int i = (d - u) * 3 + (e - v);
                    float w1v = (ch == 0) ? bw[c * 9 + i]
                                          : sw[(c * 9 + i) * 8 + (ch - 1)] * ss[c * 9 + i];
                    s += rw[c * 9 + u * 3 + v] * w1v;
                }
        }
        ws[WOFF_WC + idx] = s;
    }
}

// ---- main: composed 5x5 conv over g-channels + fused border correction
__global__ __launch_bounds__(128) void ConvKAN_main(const float* __restrict__ x,
        const float* __restrict__ wc, const float* __restrict__ w1,
        const float* __restrict__ rw, const float* __restrict__ rb,
        float* __restrict__ out) {
    __shared__ f4 A0[GD * GD];            // bases 0..3
    __shared__ f4 A1[GD * GD];            // bases 4..7
    __shared__ float S[GD * GD];          // silu
    __shared__ float featbuf[2 * 34 * NCONV];   // virtual feat rows (border blocks)

    int tid = threadIdx.x;
    int tx = tid & 31;
    int ty = tid >> 5;            // 0..3
    int r0 = ty * 8;
    int b = blockIdx.z;
    int y0 = blockIdx.y * TILE, x0 = blockIdx.x * TILE;
    const float* xb = x + (size_t)b * IMG * IMG;

    // ---- stage g for 36x36 halo
    for (int it = 0; it < 11; ++it) {
        int pos = tid + it * 128;
        if (pos < GD * GD) {
            int r = pos / GD, c = pos - r * GD;
            int gy = y0 + r - 2, gx = x0 + c - 2;
            float xv = (gy >= 0 && gy < IMG && gx >= 0 && gx < IMG) ? xb[gy * IMG + gx] : 0.f;
            float sl; f4 v0, v1;
            eval_g(xv, sl, v0, v1);     // OOB -> g(0): matches zero-padded im2col
            A0[pos] = v0; A1[pos] = v1; S[pos] = sl;
        }
    }

    float bias = rb[0];
    float acc[8];
#pragma unroll
    for (int p = 0; p < 8; ++p) acc[p] = bias;

    __syncthreads();

    bool sHt = (y0 == 0), sHb = (y0 + TILE == IMG);
    bool sVl = (x0 == 0), sVr = (x0 + TILE == IMG);
    bool sH = sHt || sHb, sV = sVl || sVr;

    // ---- border blocks: build virtual feat (1-ring outside image) from staged g
    if (sH || sV) {
        int nf0 = sH ? 34 : 0;
        int nf = nf0 + (sV ? 34 : 0);
        if (tid < nf) {
            int s, fy, fx, slot;
            if (tid < nf0) { s = 0; slot = tid; fy = sHt ? -1 : IMG; fx = x0 - 1 + tid; }
            else           { s = 1; slot = tid - nf0; fx = sVl ? -1 : IMG; fy = y0 - 1 + slot; }
            float fc[NCONV];
#pragma unroll
            for (int c = 0; c < NCONV; ++c) fc[c] = 0.f;
#pragma unroll
            for (int a = 0; a < 3; ++a) {
#pragma unroll
                for (int b2 = 0; b2 < 3; ++b2) {
                    int pos = (fy + a - 1 - (y0 - 2)) * GD + (fx + b2 - 1 - (x0 - 2));
                    f4 g0 = A0[pos]; f4 g1 = A1[pos]; float sl = S[pos];
                    int iidx = a * 3 + b2;
#pragma unroll
                    for (int c = 0; c < NCONV; ++c) {
                        const float* wp = &w1[(c * 9 + iidx) * NCH];
                        float fv = sl * wp[0];
                        fv = fmaf(g0.x, wp[1], fv); fv = fmaf(g0.y, wp[2], fv);
                        fv = fmaf(g0.z, wp[3], fv); fv = fmaf(g0.w, wp[4], fv);
                        fv = fmaf(g1.x, wp[5], fv); fv = fmaf(g1.y, wp[6], fv);
                        fv = fmaf(g1.z, wp[7], fv); fv = fmaf(g1.w, wp[8], fv);
                        fc[c] += fv;
                    }
                }
            }
#pragma unroll
            for (int c = 0; c < NCONV; ++c) featbuf[(s * 34 + slot) * NCONV + c] = fc[c];
        }
    }

    // ---- main conv: 8 rows x 1 col per thread, 60 taps, 3 LDS reads each
#pragma unroll
    for (int R = 0; R < 12; ++R) {
        int prow = (r0 + R) * GD + tx;
#pragma unroll
        for (int e = 0; e < 5; ++e) {
            int pos = prow + e;
            f4 g0 = A0[pos]; f4 g1 = A1[pos]; float sl = S[pos];
#pragma unroll
            for (int p = 0; p < 8; ++p) {
                int d = R - p;
                if (d < 0 || d > 4) continue;       // compile-time
                const float* wp = &wc[(d * 5 + e) * NCH];
                float a0 = fmaf(sl, wp[0], acc[p]);
                a0 = fmaf(g0.x, wp[1], a0); a0 = fmaf(g0.y, wp[2], a0);
                a0 = fmaf(g0.z, wp[3], a0); a0 = fmaf(g0.w, wp[4], a0);
                a0 = fmaf(g1.x, wp[5], a0); a0 = fmaf(g1.y, wp[6], a0);
                a0 = fmaf(g1.z, wp[7], a0); a0 = fmaf(g1.w, wp[8], a0);
                acc[p] = a0;
            }
        }
    }

    // ---- border correction: subtract virtual-feat contributions from own pixels
    if (sH || sV) {
        __syncthreads();
        int xg = x0 + tx;
#pragma unroll
        for (int p = 0; p < 8; ++p) {
            int yg = y0 + r0 + p;
            if (yg == 0 || yg == IMG - 1 || xg == 0 || xg == IMG - 1) {
                float dsum = 0.f;
                for (int du = -1; du <= 1; ++du) {
                    for (int dv = -1; dv <= 1; ++dv) {
                        int fy = yg + du, fx = xg + dv;
                        if (fy < 0 || fy >= IMG || fx < 0 || fx >= IMG) {
                            int s, idx;
                            if (fy < 0 || fy >= IMG) { s = 0; idx = fx - (x0 - 1); }
                            else                     { s = 1; idx = fy - (y0 - 1); }
                            const float* fb = &featbuf[(s * 34 + idx) * NCONV];
                            int rwo = (du + 1) * 3 + (dv + 1);
#pragma unroll
                            for (int c = 0; c < NCONV; ++c)
                                dsum = fmaf(rw[c * 9 + rwo], fb[c], dsum);
                        }
                    }
                }
                acc[p] -= dsum;
            }
        }
    }

    float* ob = out + ((size_t)b * IMG + y0 + r0) * IMG + x0 + tx;
#pragma unroll
    for (int p = 0; p < 8; ++p) ob[p * IMG] = acc[p];
}

extern "C" void kernel_launch(void* const* d_in, const int* in_sizes, int n_in,
                              void* d_out, int out_size, void* d_ws, size_t ws_size,
                              hipStream_t stream) {
    const float* x  = (const float*)d_in[0];
    const float* bw = (const float*)d_in[1];
    const float* sw = (const float*)d_in[2];
    const float* ss = (const float*)d_in[3];
    const float* rw = (const float*)d_in[4];
    const float* rb = (const float*)d_in[5];
    float* out = (float*)d_out;
    float* ws  = (float*)d_ws;

    ConvKAN_prep<<<1, 256, 0, stream>>>(bw, sw, ss, rw, ws);
    ConvKAN_main<<<dim3(IMG / TILE, IMG / TILE, NB), 128, 0, stream>>>(
        x, ws + WOFF_WC, ws + WOFF_W1, rw, rb, out);
}

// Round 3
// 211.644 us; speedup vs baseline: 1.1878x; 1.1878x over previous
//
#include <hip/hip_runtime.h>
#include <math.h>

#define IMG 512
#define NB 8
#define TILE 32
#define GD 36            // TILE + 4 halo
#define NCH 9            // silu + 8 bases
#define NCONV 16

// ws layout (floats): [0,225) = Wc composed 5x5x9 kernel, [256, 256+1296) = W1
#define WOFF_WC 0
#define WOFF_W1 256

typedef float f4 __attribute__((ext_vector_type(4)));

// ---- closed-form cubic B-spline bases on uniform grid t_j=(j-3)*0.4-1 + silu
__device__ __forceinline__ void eval_g(float xv, float& sl, f4& v0, f4& v1) {
    float u = fmaf(xv, 2.5f, 5.5f);
    float fi = floorf(u);
    int i = (int)fi;
    float t = u - fi;
    float s1 = 1.f - t;
    float t2 = t * t, t3 = t2 * t;
    float w0 = s1 * s1 * s1 * (1.f / 6.f);
    float w3 = t3 * (1.f / 6.f);
    float w1v = fmaf(0.5f, t3, 2.f / 3.f) - t2;          // (3t^3-6t^2+4)/6
    float msk = (u >= 0.f && u < 11.f) ? 1.f : 0.f;      // outside grid -> all bases 0
    w0 *= msk; w1v *= msk; w3 *= msk;
    float w2v = msk - w0 - w1v - w3;                     // partition of unity
    float bj[8];
#pragma unroll
    for (int j = 0; j < 8; ++j) {
        float v = 0.f;
        v = (i == j)     ? w3  : v;
        v = (i == j + 1) ? w2v : v;
        v = (i == j + 2) ? w1v : v;
        v = (i == j + 3) ? w0  : v;
        bj[j] = v;
    }
    v0 = f4{bj[0], bj[1], bj[2], bj[3]};
    v1 = f4{bj[4], bj[5], bj[6], bj[7]};
    sl = xv / (1.f + __expf(-xv));
}

// ---- prep: W1 (KAN weights over g-channels) and composed 5x5x9 kernel Wc
__global__ void ConvKAN_prep(const float* __restrict__ bw, const float* __restrict__ sw,
                             const float* __restrict__ ss, const float* __restrict__ rw,
                             float* __restrict__ ws) {
    int t = threadIdx.x;
    for (int idx = t; idx < NCONV * 9 * NCH; idx += 256) {
        int ci = idx / NCH;
        int ch = idx % NCH;
        ws[WOFF_W1 + idx] = (ch == 0) ? bw[ci] : sw[ci * 8 + (ch - 1)] * ss[ci];
    }
    for (int idx = t; idx < 25 * NCH; idx += 256) {
        int de = idx / NCH, ch = idx % NCH;
        int d = de / 5, e = de % 5;
        float s = 0.0f;
        for (int c = 0; c < NCONV; ++c) {
            int ulo = d - 2 > 0 ? d - 2 : 0, uhi = d < 2 ? d : 2;
            int vlo = e - 2 > 0 ? e - 2 : 0, vhi = e < 2 ? e : 2;
            for (int u = ulo; u <= uhi; ++u)
                for (int v = vlo; v <= vhi; ++v) {
                    int i = (d - u) * 3 + (e - v);
                    float w1v = (ch == 0) ? bw[c * 9 + i]
                                          : sw[(c * 9 + i) * 8 + (ch - 1)] * ss[c * 9 + i];
                    s += rw[c * 9 + u * 3 + v] * w1v;
                }
        }
        ws[WOFF_WC + idx] = s;
    }
}

// ---- main: composed 5x5 conv over g-channels + fused border correction
// 256 threads, 32x32 tile, 4 px/thread (column), 12 waves/CU
__global__ __launch_bounds__(256) void ConvKAN_main(const float* __restrict__ x,
        const float* __restrict__ wc, const float* __restrict__ w1,
        const float* __restrict__ rw, const float* __restrict__ rb,
        float* __restrict__ out) {
    __shared__ f4 A0[GD * GD];            // bases 0..3
    __shared__ f4 A1[GD * GD];            // bases 4..7
    __shared__ float S[GD * GD];          // silu
    __shared__ float featbuf[2 * 34 * NCONV];   // virtual feat rows (border blocks)

    int tid = threadIdx.x;
    int tx = tid & 31;
    int ty = tid >> 5;            // 0..7
    int r0 = ty * 4;              // first output row (tile coords)
    int b = blockIdx.z;
    int y0 = blockIdx.y * TILE, x0 = blockIdx.x * TILE;
    const float* xb = x + (size_t)b * IMG * IMG;

    // ---- stage g for 36x36 halo (6 strided iters)
    for (int it = 0; it < 6; ++it) {
        int pos = tid + it * 256;
        if (pos < GD * GD) {
            int r = pos / GD, c = pos - r * GD;
            int gy = y0 + r - 2, gx = x0 + c - 2;
            float xv = (gy >= 0 && gy < IMG && gx >= 0 && gx < IMG) ? xb[gy * IMG + gx] : 0.f;
            float sl; f4 v0, v1;
            eval_g(xv, sl, v0, v1);     // OOB -> g(0): matches zero-padded im2col
            A0[pos] = v0; A1[pos] = v1; S[pos] = sl;
        }
    }

    float bias = rb[0];
    float acc[4];
#pragma unroll
    for (int p = 0; p < 4; ++p) acc[p] = bias;

    __syncthreads();

    bool sHt = (y0 == 0), sHb = (y0 + TILE == IMG);
    bool sVl = (x0 == 0), sVr = (x0 + TILE == IMG);
    bool sH = sHt || sHb, sV = sVl || sVr;

    // ---- border blocks: build virtual feat (1-ring outside image) from staged g
    if (sH || sV) {
        int nf0 = sH ? 34 : 0;
        int nf = nf0 + (sV ? 34 : 0);
        if (tid < nf) {
            int s, fy, fx, slot;
            if (tid < nf0) { s = 0; slot = tid; fy = sHt ? -1 : IMG; fx = x0 - 1 + tid; }
            else           { s = 1; slot = tid - nf0; fx = sVl ? -1 : IMG; fy = y0 - 1 + slot; }
            float fc[NCONV];
#pragma unroll
            for (int c = 0; c < NCONV; ++c) fc[c] = 0.f;
#pragma unroll
            for (int a = 0; a < 3; ++a) {
#pragma unroll
                for (int b2 = 0; b2 < 3; ++b2) {
                    int pos = (fy + a - 1 - (y0 - 2)) * GD + (fx + b2 - 1 - (x0 - 2));
                    f4 g0 = A0[pos]; f4 g1 = A1[pos]; float sl = S[pos];
                    int iidx = a * 3 + b2;
#pragma unroll
                    for (int c = 0; c < NCONV; ++c) {
                        const float* wp = &w1[(c * 9 + iidx) * NCH];
                        float fv = sl * wp[0];
                        fv = fmaf(g0.x, wp[1], fv); fv = fmaf(g0.y, wp[2], fv);
                        fv = fmaf(g0.z, wp[3], fv); fv = fmaf(g0.w, wp[4], fv);
                        fv = fmaf(g1.x, wp[5], fv); fv = fmaf(g1.y, wp[6], fv);
                        fv = fmaf(g1.z, wp[7], fv); fv = fmaf(g1.w, wp[8], fv);
                        fc[c] += fv;
                    }
                }
            }
#pragma unroll
            for (int c = 0; c < NCONV; ++c) featbuf[(s * 34 + slot) * NCONV + c] = fc[c];
        }
    }

    // ---- main conv: 4 rows x 1 col per thread, 40 taps, 3 LDS reads each
#pragma unroll
    for (int R = 0; R < 8; ++R) {
        int prow = (r0 + R) * GD + tx;
#pragma unroll
        for (int e = 0; e < 5; ++e) {
            int pos = prow + e;
            f4 g0 = A0[pos]; f4 g1 = A1[pos]; float sl = S[pos];
#pragma unroll
            for (int p = 0; p < 4; ++p) {
                int d = R - p;
                if (d < 0 || d > 4) continue;       // compile-time eliminated
                const float* wp = &wc[(d * 5 + e) * NCH];
                float a0 = fmaf(sl, wp[0], acc[p]);
                a0 = fmaf(g0.x, wp[1], a0); a0 = fmaf(g0.y, wp[2], a0);
                a0 = fmaf(g0.z, wp[3], a0); a0 = fmaf(g0.w, wp[4], a0);
                a0 = fmaf(g1.x, wp[5], a0); a0 = fmaf(g1.y, wp[6], a0);
                a0 = fmaf(g1.z, wp[7], a0); a0 = fmaf(g1.w, wp[8], a0);
                acc[p] = a0;
            }
        }
    }

    // ---- border correction: subtract virtual-feat contributions from own pixels
    if (sH || sV) {
        __syncthreads();
        int xg = x0 + tx;
#pragma unroll
        for (int p = 0; p < 4; ++p) {
            int yg = y0 + r0 + p;
            if (yg == 0 || yg == IMG - 1 || xg == 0 || xg == IMG - 1) {
                float dsum = 0.f;
                for (int du = -1; du <= 1; ++du) {
                    for (int dv = -1; dv <= 1; ++dv) {
                        int fy = yg + du, fx = xg + dv;
                        if (fy < 0 || fy >= IMG || fx < 0 || fx >= IMG) {
                            int s, idx;
                            if (fy < 0 || fy >= IMG) { s = 0; idx = fx - (x0 - 1); }
                            else                     { s = 1; idx = fy - (y0 - 1); }
                            const float* fb = &featbuf[(s * 34 + idx) * NCONV];
                            int rwo = (du + 1) * 3 + (dv + 1);
#pragma unroll
                            for (int c = 0; c < NCONV; ++c)
                                dsum = fmaf(rw[c * 9 + rwo], fb[c], dsum);
                        }
                    }
                }
                acc[p] -= dsum;
            }
        }
    }

    float* ob = out + ((size_t)b * IMG + y0 + r0) * IMG + x0 + tx;
#pragma unroll
    for (int p = 0; p < 4; ++p) ob[p * IMG] = acc[p];
}

extern "C" void kernel_launch(void* const* d_in, const int* in_sizes, int n_in,
                              void* d_out, int out_size, void* d_ws, size_t ws_size,
                              hipStream_t stream) {
    const float* x  = (const float*)d_in[0];
    const float* bw = (const float*)d_in[1];
    const float* sw = (const float*)d_in[2];
    const float* ss = (const float*)d_in[3];
    const float* rw = (const float*)d_in[4];
    const float* rb = (const float*)d_in[5];
    float* out = (float*)d_out;
    float* ws  = (float*)d_ws;

    ConvKAN_prep<<<1, 256, 0, stream>>>(bw, sw, ss, rw, ws);
    ConvKAN_main<<<dim3(IMG / TILE, IMG / TILE, NB), 256, 0, stream>>>(
        x, ws + WOFF_WC, ws + WOFF_W1, rw, rb, out);
}

// Round 4
// 195.021 us; speedup vs baseline: 1.2891x; 1.0852x over previous
//
#include <hip/hip_runtime.h>
#include <math.h>

#define IMG 512
#define NB 8
#define TILE 32
#define GD 36            // TILE + 4 halo
#define NCH 9            // silu + 8 bases
#define NCONV 16

// ws layout (floats): [0,225) = Wc composed 5x5x9 kernel, [256, 256+1296) = W1
#define WOFF_WC 0
#define WOFF_W1 256

typedef float f4 __attribute__((ext_vector_type(4)));

// ---- closed-form cubic B-spline bases on uniform grid t_j=(j-3)*0.4-1 + silu
__device__ __forceinline__ void eval_g(float xv, float& sl, f4& v0, f4& v1) {
    float u = fmaf(xv, 2.5f, 5.5f);
    float fi = floorf(u);
    int i = (int)fi;
    float t = u - fi;
    float s1 = 1.f - t;
    float t2 = t * t, t3 = t2 * t;
    float w0 = s1 * s1 * s1 * (1.f / 6.f);
    float w3 = t3 * (1.f / 6.f);
    float w1v = fmaf(0.5f, t3, 2.f / 3.f) - t2;          // (3t^3-6t^2+4)/6
    float msk = (u >= 0.f && u < 11.f) ? 1.f : 0.f;      // outside grid -> all bases 0
    w0 *= msk; w1v *= msk; w3 *= msk;
    float w2v = msk - w0 - w1v - w3;                     // partition of unity
    float bj[8];
#pragma unroll
    for (int j = 0; j < 8; ++j) {
        float v = 0.f;
        v = (i == j)     ? w3  : v;
        v = (i == j + 1) ? w2v : v;
        v = (i == j + 2) ? w1v : v;
        v = (i == j + 3) ? w0  : v;
        bj[j] = v;
    }
    v0 = f4{bj[0], bj[1], bj[2], bj[3]};
    v1 = f4{bj[4], bj[5], bj[6], bj[7]};
    sl = xv / (1.f + __expf(-xv));
}

// ---- prep: W1 (KAN weights over g-channels) and composed 5x5x9 kernel Wc
__global__ void ConvKAN_prep(const float* __restrict__ bw, const float* __restrict__ sw,
                             const float* __restrict__ ss, const float* __restrict__ rw,
                             float* __restrict__ ws) {
    int t = threadIdx.x;
    for (int idx = t; idx < NCONV * 9 * NCH; idx += 256) {
        int ci = idx / NCH;
        int ch = idx % NCH;
        ws[WOFF_W1 + idx] = (ch == 0) ? bw[ci] : sw[ci * 8 + (ch - 1)] * ss[ci];
    }
    for (int idx = t; idx < 25 * NCH; idx += 256) {
        int de = idx / NCH, ch = idx % NCH;
        int d = de / 5, e = de % 5;
        float s = 0.0f;
        for (int c = 0; c < NCONV; ++c) {
            int ulo = d - 2 > 0 ? d - 2 : 0, uhi = d < 2 ? d : 2;
            int vlo = e - 2 > 0 ? e - 2 : 0, vhi = e < 2 ? e : 2;
            for (int u = ulo; u <= uhi; ++u)
                for (int v = vlo; v <= vhi; ++v) {
                    int i = (d - u) * 3 + (e - v);
                    float w1v = (ch == 0) ? bw[c * 9 + i]
                                          : sw[(c * 9 + i) * 8 + (ch - 1)] * ss[c * 9 + i];
                    s += rw[c * 9 + u * 3 + v] * w1v;
                }
        }
        ws[WOFF_WC + idx] = s;
    }
}

// ---- main: composed 5x5 conv over g-channels + fused border correction
// 256 threads, 32x32 tile, 4 px/thread. Cold paths are ROLLED (unroll 1) to
// keep code size well under the 32KB I$ (round-3 regression: ~35KB unrolled
// body thrashed I$ -> VALUBusy 25%, 124us).
__global__ __launch_bounds__(256) void ConvKAN_main(const float* __restrict__ x,
        const float* __restrict__ wc, const float* __restrict__ w1,
        const float* __restrict__ rw, const float* __restrict__ rb,
        float* __restrict__ out) {
    __shared__ f4 A0[GD * GD];            // bases 0..3
    __shared__ f4 A1[GD * GD];            // bases 4..7
    __shared__ float S[GD * GD];          // silu
    __shared__ float featbuf[2 * 34 * NCONV];   // virtual feat rows (border blocks)

    int tid = threadIdx.x;
    int tx = tid & 31;
    int ty = tid >> 5;            // 0..7
    int r0 = ty * 4;              // first output row (tile coords)
    int b = blockIdx.z;
    int y0 = blockIdx.y * TILE, x0 = blockIdx.x * TILE;
    const float* xb = x + (size_t)b * IMG * IMG;

    // ---- stage g for 36x36 halo (rolled: single eval_g instance)
#pragma unroll 1
    for (int it = 0; it < 6; ++it) {
        int pos = tid + it * 256;
        if (pos < GD * GD) {
            int r = pos / GD, c = pos - r * GD;
            int gy = y0 + r - 2, gx = x0 + c - 2;
            float xv = (gy >= 0 && gy < IMG && gx >= 0 && gx < IMG) ? xb[gy * IMG + gx] : 0.f;
            float sl; f4 v0, v1;
            eval_g(xv, sl, v0, v1);     // OOB -> g(0): matches zero-padded im2col
            A0[pos] = v0; A1[pos] = v1; S[pos] = sl;
        }
    }

    float bias = rb[0];
    float acc[4];
#pragma unroll
    for (int p = 0; p < 4; ++p) acc[p] = bias;

    __syncthreads();

    bool sHt = (y0 == 0), sHb = (y0 + TILE == IMG);
    bool sVl = (x0 == 0), sVr = (x0 + TILE == IMG);
    bool sH = sHt || sHb, sV = sVl || sVr;

    // ---- border blocks: build virtual feat (1-ring outside image) from staged g
    // c-outer rolled loop, scalar accumulator (no runtime-indexed array).
    if (sH || sV) {
        int nf0 = sH ? 34 : 0;
        int nf = nf0 + (sV ? 34 : 0);
        if (tid < nf) {
            int s, fy, fx, slot;
            if (tid < nf0) { s = 0; slot = tid; fy = sHt ? -1 : IMG; fx = x0 - 1 + tid; }
            else           { s = 1; slot = tid - nf0; fx = sVl ? -1 : IMG; fy = y0 - 1 + slot; }
            int pbase = (fy - 1 - (y0 - 2)) * GD + (fx - 1 - (x0 - 2));
#pragma unroll 1
            for (int c = 0; c < NCONV; ++c) {
                float fv = 0.f;
#pragma unroll
                for (int ab = 0; ab < 9; ++ab) {
                    int pos = pbase + (ab / 3) * GD + (ab % 3);
                    f4 g0 = A0[pos]; f4 g1 = A1[pos]; float sl = S[pos];
                    const float* wp = &w1[(c * 9 + ab) * NCH];
                    float t0 = sl * wp[0];
                    t0 = fmaf(g0.x, wp[1], t0); t0 = fmaf(g0.y, wp[2], t0);
                    t0 = fmaf(g0.z, wp[3], t0); t0 = fmaf(g0.w, wp[4], t0);
                    t0 = fmaf(g1.x, wp[5], t0); t0 = fmaf(g1.y, wp[6], t0);
                    t0 = fmaf(g1.z, wp[7], t0); t0 = fmaf(g1.w, wp[8], t0);
                    fv += t0;
                }
                featbuf[(s * 34 + slot) * NCONV + c] = fv;
            }
        }
    }

    // ---- HOT: 4 rows x 1 col per thread, 40 taps, 3 LDS reads each (unrolled)
#pragma unroll
    for (int R = 0; R < 8; ++R) {
        int prow = (r0 + R) * GD + tx;
#pragma unroll
        for (int e = 0; e < 5; ++e) {
            int pos = prow + e;
            f4 g0 = A0[pos]; f4 g1 = A1[pos]; float sl = S[pos];
#pragma unroll
            for (int p = 0; p < 4; ++p) {
                int d = R - p;
                if (d < 0 || d > 4) continue;       // compile-time eliminated
                const float* wp = &wc[(d * 5 + e) * NCH];
                float a0 = fmaf(sl, wp[0], acc[p]);
                a0 = fmaf(g0.x, wp[1], a0); a0 = fmaf(g0.y, wp[2], a0);
                a0 = fmaf(g0.z, wp[3], a0); a0 = fmaf(g0.w, wp[4], a0);
                a0 = fmaf(g1.x, wp[5], a0); a0 = fmaf(g1.y, wp[6], a0);
                a0 = fmaf(g1.z, wp[7], a0); a0 = fmaf(g1.w, wp[8], a0);
                acc[p] = a0;
            }
        }
    }

    // ---- border correction: rolled du/dv loop; subtract virtual-feat terms
    if (sH || sV) {
        __syncthreads();
        int xg = x0 + tx;
#pragma unroll
        for (int p = 0; p < 4; ++p) {
            int yg = y0 + r0 + p;
            if (yg == 0 || yg == IMG - 1 || xg == 0 || xg == IMG - 1) {
                float dsum = 0.f;
#pragma unroll 1
                for (int dd = 0; dd < 9; ++dd) {
                    int du = dd / 3 - 1, dv = dd % 3 - 1;
                    int fy = yg + du, fx = xg + dv;
                    if (fy < 0 || fy >= IMG || fx < 0 || fx >= IMG) {
                        int s, idx;
                        if (fy < 0 || fy >= IMG) { s = 0; idx = fx - (x0 - 1); }
                        else                     { s = 1; idx = fy - (y0 - 1); }
                        const float* fb = &featbuf[(s * 34 + idx) * NCONV];
                        int rwo = dd;   // (du+1)*3 + (dv+1)
#pragma unroll
                        for (int c = 0; c < NCONV; ++c)
                            dsum = fmaf(rw[c * 9 + rwo], fb[c], dsum);
                    }
                }
                acc[p] -= dsum;
            }
        }
    }

    float* ob = out + ((size_t)b * IMG + y0 + r0) * IMG + x0 + tx;
#pragma unroll
    for (int p = 0; p < 4; ++p) ob[p * IMG] = acc[p];
}

extern "C" void kernel_launch(void* const* d_in, const int* in_sizes, int n_in,
                              void* d_out, int out_size, void* d_ws, size_t ws_size,
                              hipStream_t stream) {
    const float* x  = (const float*)d_in[0];
    const float* bw = (const float*)d_in[1];
    const float* sw = (const float*)d_in[2];
    const float* ss = (const float*)d_in[3];
    const float* rw = (const float*)d_in[4];
    const float* rb = (const float*)d_in[5];
    float* out = (float*)d_out;
    float* ws  = (float*)d_ws;

    ConvKAN_prep<<<1, 256, 0, stream>>>(bw, sw, ss, rw, ws);
    ConvKAN_main<<<dim3(IMG / TILE, IMG / TILE, NB), 256, 0, stream>>>(
        x, ws + WOFF_WC, ws + WOFF_W1, rw, rb, out);
}

// Round 6
// 182.484 us; speedup vs baseline: 1.3776x; 1.0687x over previous
//
#include <hip/hip_runtime.h>
#include <math.h>

#define IMG 512
#define NB 8
#define TILE 32
#define GD 36            // TILE + 4 halo
#define NCH 9            // silu + 8 bases
#define NCONV 16
#define NPOS (GD * GD)   // 1296

// ws layout (floats): [0,225) = Wc composed 5x5x9 kernel, [256, 256+1296) = W1
#define WOFF_WC 0
#define WOFF_W1 256

typedef float f4 __attribute__((ext_vector_type(4)));

// ---- closed-form cubic B-spline bases on uniform grid t_j=(j-3)*0.4-1 + silu
__device__ __forceinline__ void eval_g(float xv, float& sl, f4& v0, f4& v1) {
    float u = fmaf(xv, 2.5f, 5.5f);
    float fi = floorf(u);
    int i = (int)fi;
    float t = u - fi;
    float s1 = 1.f - t;
    float t2 = t * t, t3 = t2 * t;
    float w0 = s1 * s1 * s1 * (1.f / 6.f);
    float w3 = t3 * (1.f / 6.f);
    float w1v = fmaf(0.5f, t3, 2.f / 3.f) - t2;          // (3t^3-6t^2+4)/6
    float msk = (u >= 0.f && u < 11.f) ? 1.f : 0.f;      // outside grid -> all bases 0
    w0 *= msk; w1v *= msk; w3 *= msk;
    float w2v = msk - w0 - w1v - w3;                     // partition of unity
    float bj[8];
#pragma unroll
    for (int j = 0; j < 8; ++j) {
        float v = 0.f;
        v = (i == j)     ? w3  : v;
        v = (i == j + 1) ? w2v : v;
        v = (i == j + 2) ? w1v : v;
        v = (i == j + 3) ? w0  : v;
        bj[j] = v;
    }
    v0 = f4{bj[0], bj[1], bj[2], bj[3]};
    v1 = f4{bj[4], bj[5], bj[6], bj[7]};
    sl = xv / (1.f + __expf(-xv));
}

// ---- prep: W1 (KAN weights over g-channels) and composed 5x5x9 kernel Wc
__global__ void ConvKAN_prep(const float* __restrict__ bw, const float* __restrict__ sw,
                             const float* __restrict__ ss, const float* __restrict__ rw,
                             float* __restrict__ ws) {
    int t = threadIdx.x;
    for (int idx = t; idx < NCONV * 9 * NCH; idx += 256) {
        int ci = idx / NCH;
        int ch = idx % NCH;
        ws[WOFF_W1 + idx] = (ch == 0) ? bw[ci] : sw[ci * 8 + (ch - 1)] * ss[ci];
    }
    for (int idx = t; idx < 25 * NCH; idx += 256) {
        int de = idx / NCH, ch = idx % NCH;
        int d = de / 5, e = de % 5;
        float s = 0.0f;
        for (int c = 0; c < NCONV; ++c) {
            int ulo = d - 2 > 0 ? d - 2 : 0, uhi = d < 2 ? d : 2;
            int vlo = e - 2 > 0 ? e - 2 : 0, vhi = e < 2 ? e : 2;
            for (int u = ulo; u <= uhi; ++u)
                for (int v = vlo; v <= vhi; ++v) {
                    int i = (d - u) * 3 + (e - v);
                    float w1v = (ch == 0) ? bw[c * 9 + i]
                                          : sw[(c * 9 + i) * 8 + (ch - 1)] * ss[c * 9 + i];
                    s += rw[c * 9 + u * 3 + v] * w1v;
                }
        }
        ws[WOFF_WC + idx] = s;
    }
}

// ---- main: composed 5x5 conv over g-channels + fused border correction.
// ALL hot-loop memory traffic is DS (weights staged to LDS): avoids SMEM/DS
// lgkmcnt mixing (SMEM returns out-of-order -> forces lgkmcnt(0) drains).
__global__ __launch_bounds__(256) void ConvKAN_main(const float* __restrict__ x,
        const float* __restrict__ wc, const float* __restrict__ w1,
        const float* __restrict__ rw, const float* __restrict__ rb,
        float* __restrict__ out) {
    __shared__ f4 A0[NPOS];               // bases 0..3
    __shared__ f4 A1[NPOS];               // bases 4..7
    __shared__ float S[NPOS];             // silu
    __shared__ f4 WA0[25];                // tap weights for ch 1..4
    __shared__ f4 WA1[25];                // tap weights for ch 5..8
    __shared__ float WS[25];              // tap weight for ch 0 (silu)
    __shared__ float featbuf[2 * 34 * NCONV];   // virtual feat rows (border blocks)

    int tid = threadIdx.x;
    int tx = tid & 31;
    int ty = tid >> 5;            // 0..7
    int r0 = ty * 4;              // first output row (tile coords)
    int b = blockIdx.z;
    int y0 = blockIdx.y * TILE, x0 = blockIdx.x * TILE;
    const float* xb = x + (size_t)b * IMG * IMG;

    // ---- stage g for 36x36 halo (rolled: single eval_g instance)
#pragma unroll 1
    for (int it = 0; it < 6; ++it) {
        int pos = tid + it * 256;
        if (pos < NPOS) {
            int r = pos / GD, c = pos - r * GD;
            int gy = y0 + r - 2, gx = x0 + c - 2;
            float xv = (gy >= 0 && gy < IMG && gx >= 0 && gx < IMG) ? xb[gy * IMG + gx] : 0.f;
            float sl; f4 v0, v1;
            eval_g(xv, sl, v0, v1);     // OOB -> g(0): matches zero-padded im2col
            A0[pos] = v0; A1[pos] = v1; S[pos] = sl;
        }
    }
    // ---- stage composed weights to LDS (broadcast-read in hot loop)
    if (tid < 25) {
        const float* wp = &wc[tid * NCH];
        WA0[tid] = f4{wp[1], wp[2], wp[3], wp[4]};
        WA1[tid] = f4{wp[5], wp[6], wp[7], wp[8]};
        WS[tid]  = wp[0];
    }

    float bias = rb[0];
    float accA[4], accB[4];
#pragma unroll
    for (int p = 0; p < 4; ++p) { accA[p] = bias; accB[p] = 0.f; }

    __syncthreads();

    bool sHt = (y0 == 0), sHb = (y0 + TILE == IMG);
    bool sVl = (x0 == 0), sVr = (x0 + TILE == IMG);
    bool sH = sHt || sHb, sV = sVl || sVr;

    // ---- border blocks: build virtual feat (1-ring outside image) from staged g
    if (sH || sV) {
        int nf0 = sH ? 34 : 0;
        int nf = nf0 + (sV ? 34 : 0);
        if (tid < nf) {
            int s, fy, fx, slot;
            if (tid < nf0) { s = 0; slot = tid; fy = sHt ? -1 : IMG; fx = x0 - 1 + tid; }
            else           { s = 1; slot = tid - nf0; fx = sVl ? -1 : IMG; fy = y0 - 1 + slot; }
            int pbase = (fy - 1 - (y0 - 2)) * GD + (fx - 1 - (x0 - 2));
#pragma unroll 1
            for (int c = 0; c < NCONV; ++c) {
                float fv = 0.f;
#pragma unroll
                for (int ab = 0; ab < 9; ++ab) {
                    int pos = pbase + (ab / 3) * GD + (ab % 3);
                    f4 g0 = A0[pos]; f4 g1 = A1[pos]; float sl = S[pos];
                    const float* wp = &w1[(c * 9 + ab) * NCH];
                    float t0 = sl * wp[0];
                    t0 = fmaf(g0.x, wp[1], t0); t0 = fmaf(g0.y, wp[2], t0);
                    t0 = fmaf(g0.z, wp[3], t0); t0 = fmaf(g0.w, wp[4], t0);
                    t0 = fmaf(g1.x, wp[5], t0); t0 = fmaf(g1.y, wp[6], t0);
                    t0 = fmaf(g1.z, wp[7], t0); t0 = fmaf(g1.w, wp[8], t0);
                    fv += t0;
                }
                featbuf[(s * 34 + slot) * NCONV + c] = fv;
            }
        }
    }

    // ---- HOT: 4 rows x 1 col per thread, 40 g-taps; all reads DS with
    // static immediate offsets; dual accumulators (e<3 / e>=3) for ILP.
#pragma unroll
    for (int R = 0; R < 8; ++R) {
#pragma unroll
        for (int e = 0; e < 5; ++e) {
            int pos = (r0 + R) * GD + tx + e;
            f4 g0 = A0[pos]; f4 g1 = A1[pos]; float sl = S[pos];
#pragma unroll
            for (int p = 0; p < 4; ++p) {
                int d = R - p;
                if (d < 0 || d > 4) continue;       // compile-time eliminated
                int t = d * 5 + e;
                f4 w0 = WA0[t]; f4 w1r = WA1[t]; float w8 = WS[t];
                float a0 = (e < 3) ? accA[p] : accB[p];
                a0 = fmaf(sl, w8, a0);
                a0 = fmaf(g0.x, w0.x, a0); a0 = fmaf(g0.y, w0.y, a0);
                a0 = fmaf(g0.z, w0.z, a0); a0 = fmaf(g0.w, w0.w, a0);
                a0 = fmaf(g1.x, w1r.x, a0); a0 = fmaf(g1.y, w1r.y, a0);
                a0 = fmaf(g1.z, w1r.z, a0); a0 = fmaf(g1.w, w1r.w, a0);
                if (e < 3) accA[p] = a0; else accB[p] = a0;
            }
        }
    }
    float acc[4];
#pragma unroll
    for (int p = 0; p < 4; ++p) acc[p] = accA[p] + accB[p];

    // ---- border correction: rolled; subtract virtual-feat terms
    if (sH || sV) {
        __syncthreads();
        int xg = x0 + tx;
#pragma unroll
        for (int p = 0; p < 4; ++p) {
            int yg = y0 + r0 + p;
            if (yg == 0 || yg == IMG - 1 || xg == 0 || xg == IMG - 1) {
                float dsum = 0.f;
#pragma unroll 1
                for (int dd = 0; dd < 9; ++dd) {
                    int du = dd / 3 - 1, dv = dd % 3 - 1;
                    int fy = yg + du, fx = xg + dv;
                    if (fy < 0 || fy >= IMG || fx < 0 || fx >= IMG) {
                        int s, idx;
                        if (fy < 0 || fy >= IMG) { s = 0; idx = fx - (x0 - 1); }
                        else                     { s = 1; idx = fy - (y0 - 1); }
                        const float* fb = &featbuf[(s * 34 + idx) * NCONV];
#pragma unroll
                        for (int c = 0; c < NCONV; ++c)
                            dsum = fmaf(rw[c * 9 + dd], fb[c], dsum);
                    }
                }
                acc[p] -= dsum;
            }
        }
    }

    float* ob = out + ((size_t)b * IMG + y0 + r0) * IMG + x0 + tx;
#pragma unroll
    for (int p = 0; p < 4; ++p) ob[p * IMG] = acc[p];
}

extern "C" void kernel_launch(void* const* d_in, const int* in_sizes, int n_in,
                              void* d_out, int out_size, void* d_ws, size_t ws_size,
                              hipStream_t stream) {
    const float* x  = (const float*)d_in[0];
    const float* bw = (const float*)d_in[1];
    const float* sw = (const float*)d_in[2];
    const float* ss = (const float*)d_in[3];
    const float* rw = (const float*)d_in[4];
    const float* rb = (const float*)d_in[5];
    float* out = (float*)d_out;
    float* ws  = (float*)d_ws;

    ConvKAN_prep<<<1, 256, 0, stream>>>(bw, sw, ss, rw, ws);
    ConvKAN_main<<<dim3(IMG / TILE, IMG / TILE, NB), 256, 0, stream>>>(
        x, ws + WOFF_WC, ws + WOFF_W1, rw, rb, out);
}

// Round 7
// 163.334 us; speedup vs baseline: 1.5391x; 1.1172x over previous
//
#include <hip/hip_runtime.h>
#include <math.h>

#define IMG_H 512
#define IMG_W 512
#define NBATCH 8
#define TILE 32
#define GDIM 36            // TILE + 4 halo
#define NCH 9              // g channels: silu + 8 bases
#define NCONV 16

// ws layout (floats): [0,225) = Wc composed 5x5x9 kernel, [256, 256+1296) = W1 (16 x 9pos x 9ch)
#define WOFF_WC 0
#define WOFF_W1 256

// ---- g(x) = [silu(x), B0..B7(x)] : closed-form cubic B-spline bases on uniform
// grid t_j=(j-3)*0.4-1. u = x*2.5+5.5 maps knots to integers; i=floor(u), t=u-i.
__device__ __forceinline__ void eval_g(float x, float g[NCH]) {
    float u = fmaf(x, 2.5f, 5.5f);
    float fi = floorf(u);
    int i = (int)fi;
    float t = u - fi;
    float s1 = 1.f - t;
    float t2 = t * t, t3 = t2 * t;
    float w0 = s1 * s1 * s1 * (1.f / 6.f);
    float w3 = t3 * (1.f / 6.f);
    float w1v = fmaf(0.5f, t3, 2.f / 3.f) - t2;          // (3t^3-6t^2+4)/6
    float msk = (u >= 0.f && u < 11.f) ? 1.f : 0.f;      // outside grid -> all bases 0
    w0 *= msk; w1v *= msk; w3 *= msk;
    float w2v = msk - w0 - w1v - w3;                     // partition of unity
    g[0] = x / (1.f + __expf(-x));                       // silu
#pragma unroll
    for (int j = 0; j < 8; ++j) {
        float v = 0.f;
        v = (i == j)     ? w3  : v;
        v = (i == j + 1) ? w2v : v;
        v = (i == j + 2) ? w1v : v;
        v = (i == j + 3) ? w0  : v;
        g[j + 1] = v;
    }
}

// ---- prep: build W1 (KAN conv weights over g-channels) and composed 5x5 kernel Wc
__global__ void ConvKAN_prep(const float* __restrict__ bw, const float* __restrict__ sw,
                             const float* __restrict__ ss, const float* __restrict__ rw,
                             float* __restrict__ ws) {
    int t = threadIdx.x;
    // W1[(c*9 + i)*9 + ch], i = ky*3+kx
    for (int idx = t; idx < NCONV * 9 * NCH; idx += 256) {
        int ci = idx / NCH;      // c*9 + i
        int ch = idx % NCH;
        ws[WOFF_W1 + idx] = (ch == 0) ? bw[ci] : sw[ci * 8 + (ch - 1)] * ss[ci];
    }
    // Wc[(d*5+e)*9 + ch] = sum_c sum_{u,v} rw[c,u,v] * W1[c,ch,d-u,e-v]
    for (int idx = t; idx < 25 * NCH; idx += 256) {
        int de = idx / NCH, ch = idx % NCH;
        int d = de / 5, e = de % 5;
        float s = 0.0f;
        for (int c = 0; c < NCONV; ++c) {
            int ulo = d - 2 > 0 ? d - 2 : 0, uhi = d < 2 ? d : 2;
            int vlo = e - 2 > 0 ? e - 2 : 0, vhi = e < 2 ? e : 2;
            for (int u = ulo; u <= uhi; ++u)
                for (int v = vlo; v <= vhi; ++v) {
                    int i = (d - u) * 3 + (e - v);
                    float w1v = (ch == 0) ? bw[c * 9 + i]
                                          : sw[(c * 9 + i) * 8 + (ch - 1)] * ss[c * 9 + i];
                    s += rw[c * 9 + u * 3 + v] * w1v;
                }
        }
        ws[WOFF_WC + idx] = s;
    }
}

// ---- main: composed 5x5 conv over g-channels, g staged in LDS per 32x32 tile
// EXACT round-1 structure (45.5us baseline); only eval_g is closed-form now.
__global__ __launch_bounds__(256) void ConvKAN_main(const float* __restrict__ x,
                                                    const float* __restrict__ wc,
                                                    const float* __restrict__ rb,
                                                    float* __restrict__ out) {
    __shared__ float gld[GDIM * GDIM * NCH];
    int tid = threadIdx.x;
    int b = blockIdx.z;
    int y0 = blockIdx.y * TILE, x0 = blockIdx.x * TILE;
    const float* xb = x + (size_t)b * IMG_H * IMG_W;

    for (int i = tid; i < GDIM * GDIM; i += 256) {
        int r = i / GDIM, c = i % GDIM;
        int gy = y0 + r - 2, gx = x0 + c - 2;
        float xv = (gy >= 0 && gy < IMG_H && gx >= 0 && gx < IMG_W) ? xb[gy * IMG_W + gx] : 0.0f;
        float g[NCH];
        eval_g(xv, g);   // OOB -> g(0): matches zero-padded im2col semantics
#pragma unroll
        for (int j = 0; j < NCH; ++j) gld[i * NCH + j] = g[j];
    }
    __syncthreads();

    int tx = tid & 31;
    int ty = tid >> 5;          // 0..7
    int r0 = ty * 4;            // first output row (tile coords) of this thread
    float bias = rb[0];
    float acc[4] = {bias, bias, bias, bias};

#pragma unroll
    for (int R = 0; R < 8; ++R) {       // g rows r0+R cover rows needed by pixels p=0..3
#pragma unroll
        for (int e = 0; e < 5; ++e) {
            const float* gp = &gld[((r0 + R) * GDIM + tx + e) * NCH];
            float gv[NCH];
#pragma unroll
            for (int ch = 0; ch < NCH; ++ch) gv[ch] = gp[ch];
#pragma unroll
            for (int p = 0; p < 4; ++p) {
                int d = R - p;
                if (d < 0 || d > 4) continue;          // compile-time eliminated
                const float* wp = &wc[(d * 5 + e) * NCH];
#pragma unroll
                for (int ch = 0; ch < NCH; ++ch)
                    acc[p] = fmaf(gv[ch], wp[ch], acc[p]);
            }
        }
    }
    float* ob = out + ((size_t)b * IMG_H + y0) * IMG_W + x0;
#pragma unroll
    for (int p = 0; p < 4; ++p)
        ob[(r0 + p) * IMG_W + tx] = acc[p];
}

// ---- border correction: subtract contributions of "virtual feat" at the 1-ring outside image
__global__ void ConvKAN_corr(const float* __restrict__ x, const float* __restrict__ w1,
                             const float* __restrict__ rw, float* __restrict__ out) {
    int t = blockIdx.x * 256 + threadIdx.x;
    const int RING = 2 * (IMG_W + 2) + 2 * IMG_H;  // 2052
    if (t >= NBATCH * RING) return;
    int b = t / RING, r = t % RING;
    int fy, fx;
    if (r < IMG_W + 2)            { fy = -1;            fx = r - 1; }
    else if (r < 2 * (IMG_W + 2)) { fy = IMG_H;         fx = (r - (IMG_W + 2)) - 1; }
    else if (r < 2 * (IMG_W + 2) + IMG_H) { fy = r - 2 * (IMG_W + 2); fx = -1; }
    else                          { fy = r - (2 * (IMG_W + 2) + IMG_H); fx = IMG_W; }

    const float* xb = x + (size_t)b * IMG_H * IMG_W;
    float fc[NCONV];
#pragma unroll
    for (int c = 0; c < NCONV; ++c) fc[c] = 0.0f;

#pragma unroll
    for (int a = 0; a < 3; ++a) {
#pragma unroll
        for (int bb = 0; bb < 3; ++bb) {
            int gy = fy + a - 1, gx = fx + bb - 1;
            float xv = (gy >= 0 && gy < IMG_H && gx >= 0 && gx < IMG_W) ? xb[gy * IMG_W + gx] : 0.0f;
            float g[NCH];
            eval_g(xv, g);
            int i = a * 3 + bb;
#pragma unroll
            for (int c = 0; c < NCONV; ++c) {
                const float* wp = &w1[(c * 9 + i) * NCH];
                float s = 0.0f;
#pragma unroll
                for (int ch = 0; ch < NCH; ++ch) s += wp[ch] * g[ch];
                fc[c] += s;
            }
        }
    }
    // scatter: out(fy-u+1, fx-v+1) -= sum_c rw[c,u,v]*fc[c]
#pragma unroll
    for (int u = 0; u < 3; ++u) {
#pragma unroll
        for (int v = 0; v < 3; ++v) {
            int ty = fy - (u - 1), tx2 = fx - (v - 1);
            if (ty >= 0 && ty < IMG_H && tx2 >= 0 && tx2 < IMG_W) {
                float s = 0.0f;
#pragma unroll
                for (int c = 0; c < NCONV; ++c) s += rw[c * 9 + u * 3 + v] * fc[c];
                atomicAdd(&out[((size_t)b * IMG_H + ty) * IMG_W + tx2], -s);
            }
        }
    }
}

extern "C" void kernel_launch(void* const* d_in, const int* in_sizes, int n_in,
                              void* d_out, int out_size, void* d_ws, size_t ws_size,
                              hipStream_t stream) {
    const float* x  = (const float*)d_in[0];
    const float* bw = (const float*)d_in[1];
    const float* sw = (const float*)d_in[2];
    const float* ss = (const float*)d_in[3];
    const float* rw = (const float*)d_in[4];
    const float* rb = (const float*)d_in[5];
    float* out = (float*)d_out;
    float* ws  = (float*)d_ws;

    ConvKAN_prep<<<1, 256, 0, stream>>>(bw, sw, ss, rw, ws);
    ConvKAN_main<<<dim3(IMG_W / TILE, IMG_H / TILE, NBATCH), 256, 0, stream>>>(
        x, ws + WOFF_WC, rb, out);
    const int RING = 2 * (IMG_W + 2) + 2 * IMG_H;
    int nthr = NBATCH * RING;
    ConvKAN_corr<<<(nthr + 255) / 256, 256, 0, stream>>>(x, ws + WOFF_W1, rw, out);
}

// Round 8
// 157.749 us; speedup vs baseline: 1.5936x; 1.0354x over previous
//
#include <hip/hip_runtime.h>
#include <math.h>

#define IMG_H 512
#define IMG_W 512
#define NBATCH 8
#define TILE 32
#define GDIM 36            // TILE + 4 halo
#define NCH 9              // g channels: silu + 8 bases
#define NCONV 16
#define NPOS (GDIM * GDIM)

// ws layout (floats): [0,225) = Wc composed 5x5x9 kernel, [256, 256+1296) = W1 (16 x 9pos x 9ch)
#define WOFF_WC 0
#define WOFF_W1 256

typedef float f4 __attribute__((ext_vector_type(4)));

// ---- g(x) = [silu(x), B0..B7(x)] : closed-form cubic B-spline bases on uniform
// grid t_j=(j-3)*0.4-1. u = x*2.5+5.5 maps knots to integers; i=floor(u), t=u-i.
__device__ __forceinline__ void eval_g4(float x, float& sl, f4& v0, f4& v1) {
    float u = fmaf(x, 2.5f, 5.5f);
    float fi = floorf(u);
    int i = (int)fi;
    float t = u - fi;
    float s1 = 1.f - t;
    float t2 = t * t, t3 = t2 * t;
    float w0 = s1 * s1 * s1 * (1.f / 6.f);
    float w3 = t3 * (1.f / 6.f);
    float w1v = fmaf(0.5f, t3, 2.f / 3.f) - t2;          // (3t^3-6t^2+4)/6
    float msk = (u >= 0.f && u < 11.f) ? 1.f : 0.f;      // outside grid -> all bases 0
    w0 *= msk; w1v *= msk; w3 *= msk;
    float w2v = msk - w0 - w1v - w3;                     // partition of unity
    sl = x / (1.f + __expf(-x));                         // silu
    float bj[8];
#pragma unroll
    for (int j = 0; j < 8; ++j) {
        float v = 0.f;
        v = (i == j)     ? w3  : v;
        v = (i == j + 1) ? w2v : v;
        v = (i == j + 2) ? w1v : v;
        v = (i == j + 3) ? w0  : v;
        bj[j] = v;
    }
    v0 = f4{bj[0], bj[1], bj[2], bj[3]};
    v1 = f4{bj[4], bj[5], bj[6], bj[7]};
}

__device__ __forceinline__ void eval_g(float x, float g[NCH]) {
    float sl; f4 v0, v1;
    eval_g4(x, sl, v0, v1);
    g[0] = sl;
    g[1] = v0.x; g[2] = v0.y; g[3] = v0.z; g[4] = v0.w;
    g[5] = v1.x; g[6] = v1.y; g[7] = v1.z; g[8] = v1.w;
}

// ---- prep: build W1 (KAN conv weights over g-channels) and composed 5x5 kernel Wc
__global__ void ConvKAN_prep(const float* __restrict__ bw, const float* __restrict__ sw,
                             const float* __restrict__ ss, const float* __restrict__ rw,
                             float* __restrict__ ws) {
    int t = threadIdx.x;
    // W1[(c*9 + i)*9 + ch], i = ky*3+kx
    for (int idx = t; idx < NCONV * 9 * NCH; idx += 256) {
        int ci = idx / NCH;      // c*9 + i
        int ch = idx % NCH;
        ws[WOFF_W1 + idx] = (ch == 0) ? bw[ci] : sw[ci * 8 + (ch - 1)] * ss[ci];
    }
    // Wc[(d*5+e)*9 + ch] = sum_c sum_{u,v} rw[c,u,v] * W1[c,ch,d-u,e-v]
    for (int idx = t; idx < 25 * NCH; idx += 256) {
        int de = idx / NCH, ch = idx % NCH;
        int d = de / 5, e = de % 5;
        float s = 0.0f;
        for (int c = 0; c < NCONV; ++c) {
            int ulo = d - 2 > 0 ? d - 2 : 0, uhi = d < 2 ? d : 2;
            int vlo = e - 2 > 0 ? e - 2 : 0, vhi = e < 2 ? e : 2;
            for (int u = ulo; u <= uhi; ++u)
                for (int v = vlo; v <= vhi; ++v) {
                    int i = (d - u) * 3 + (e - v);
                    float w1v = (ch == 0) ? bw[c * 9 + i]
                                          : sw[(c * 9 + i) * 8 + (ch - 1)] * ss[c * 9 + i];
                    s += rw[c * 9 + u * 3 + v] * w1v;
                }
        }
        ws[WOFF_WC + idx] = s;
    }
}

// ---- main: round-7 structure; ONE change: f4 g-layout (A0/A1/S), 3 LDS reads/tap
__global__ __launch_bounds__(256) void ConvKAN_main(const float* __restrict__ x,
                                                    const float* __restrict__ wc,
                                                    const float* __restrict__ rb,
                                                    float* __restrict__ out) {
    __shared__ f4 A0[NPOS];       // bases 0..3
    __shared__ f4 A1[NPOS];       // bases 4..7
    __shared__ float S[NPOS];     // silu
    int tid = threadIdx.x;
    int b = blockIdx.z;
    int y0 = blockIdx.y * TILE, x0 = blockIdx.x * TILE;
    const float* xb = x + (size_t)b * IMG_H * IMG_W;

    for (int i = tid; i < NPOS; i += 256) {
        int r = i / GDIM, c = i % GDIM;
        int gy = y0 + r - 2, gx = x0 + c - 2;
        float xv = (gy >= 0 && gy < IMG_H && gx >= 0 && gx < IMG_W) ? xb[gy * IMG_W + gx] : 0.0f;
        float sl; f4 v0, v1;
        eval_g4(xv, sl, v0, v1);   // OOB -> g(0): matches zero-padded im2col semantics
        A0[i] = v0; A1[i] = v1; S[i] = sl;
    }
    __syncthreads();

    int tx = tid & 31;
    int ty = tid >> 5;          // 0..7
    int r0 = ty * 4;            // first output row (tile coords) of this thread
    float bias = rb[0];
    float acc[4] = {bias, bias, bias, bias};

#pragma unroll
    for (int R = 0; R < 8; ++R) {       // g rows r0+R cover rows needed by pixels p=0..3
#pragma unroll
        for (int e = 0; e < 5; ++e) {
            int pos = (r0 + R) * GDIM + tx + e;
            f4 g0 = A0[pos]; f4 g1 = A1[pos]; float sl = S[pos];
#pragma unroll
            for (int p = 0; p < 4; ++p) {
                int d = R - p;
                if (d < 0 || d > 4) continue;          // compile-time eliminated
                const float* wp = &wc[(d * 5 + e) * NCH];
                float a0 = fmaf(sl, wp[0], acc[p]);
                a0 = fmaf(g0.x, wp[1], a0); a0 = fmaf(g0.y, wp[2], a0);
                a0 = fmaf(g0.z, wp[3], a0); a0 = fmaf(g0.w, wp[4], a0);
                a0 = fmaf(g1.x, wp[5], a0); a0 = fmaf(g1.y, wp[6], a0);
                a0 = fmaf(g1.z, wp[7], a0); a0 = fmaf(g1.w, wp[8], a0);
                acc[p] = a0;
            }
        }
    }
    float* ob = out + ((size_t)b * IMG_H + y0) * IMG_W + x0;
#pragma unroll
    for (int p = 0; p < 4; ++p)
        ob[(r0 + p) * IMG_W + tx] = acc[p];
}

// ---- border correction: subtract contributions of "virtual feat" at the 1-ring outside image
__global__ void ConvKAN_corr(const float* __restrict__ x, const float* __restrict__ w1,
                             const float* __restrict__ rw, float* __restrict__ out) {
    int t = blockIdx.x * 256 + threadIdx.x;
    const int RING = 2 * (IMG_W + 2) + 2 * IMG_H;  // 2052
    if (t >= NBATCH * RING) return;
    int b = t / RING, r = t % RING;
    int fy, fx;
    if (r < IMG_W + 2)            { fy = -1;            fx = r - 1; }
    else if (r < 2 * (IMG_W + 2)) { fy = IMG_H;         fx = (r - (IMG_W + 2)) - 1; }
    else if (r < 2 * (IMG_W + 2) + IMG_H) { fy = r - 2 * (IMG_W + 2); fx = -1; }
    else                          { fy = r - (2 * (IMG_W + 2) + IMG_H); fx = IMG_W; }

    const float* xb = x + (size_t)b * IMG_H * IMG_W;
    float fc[NCONV];
#pragma unroll
    for (int c = 0; c < NCONV; ++c) fc[c] = 0.0f;

#pragma unroll
    for (int a = 0; a < 3; ++a) {
#pragma unroll
        for (int bb = 0; bb < 3; ++bb) {
            int gy = fy + a - 1, gx = fx + bb - 1;
            float xv = (gy >= 0 && gy < IMG_H && gx >= 0 && gx < IMG_W) ? xb[gy * IMG_W + gx] : 0.0f;
            float g[NCH];
            eval_g(xv, g);
            int i = a * 3 + bb;
#pragma unroll
            for (int c = 0; c < NCONV; ++c) {
                const float* wp = &w1[(c * 9 + i) * NCH];
                float s = 0.0f;
#pragma unroll
                for (int ch = 0; ch < NCH; ++ch) s += wp[ch] * g[ch];
                fc[c] += s;
            }
        }
    }
    // scatter: out(fy-u+1, fx-v+1) -= sum_c rw[c,u,v]*fc[c]
#pragma unroll
    for (int u = 0; u < 3; ++u) {
#pragma unroll
        for (int v = 0; v < 3; ++v) {
            int ty = fy - (u - 1), tx2 = fx - (v - 1);
            if (ty >= 0 && ty < IMG_H && tx2 >= 0 && tx2 < IMG_W) {
                float s = 0.0f;
#pragma unroll
                for (int c = 0; c < NCONV; ++c) s += rw[c * 9 + u * 3 + v] * fc[c];
                atomicAdd(&out[((size_t)b * IMG_H + ty) * IMG_W + tx2], -s);
            }
        }
    }
}

extern "C" void kernel_launch(void* const* d_in, const int* in_sizes, int n_in,
                              void* d_out, int out_size, void* d_ws, size_t ws_size,
                              hipStream_t stream) {
    const float* x  = (const float*)d_in[0];
    const float* bw = (const float*)d_in[1];
    const float* sw = (const float*)d_in[2];
    const float* ss = (const float*)d_in[3];
    const float* rw = (const float*)d_in[4];
    const float* rb = (const float*)d_in[5];
    float* out = (float*)d_out;
    float* ws  = (float*)d_ws;

    ConvKAN_prep<<<1, 256, 0, stream>>>(bw, sw, ss, rw, ws);
    ConvKAN_main<<<dim3(IMG_W / TILE, IMG_H / TILE, NBATCH), 256, 0, stream>>>(
        x, ws + WOFF_WC, rb, out);
    const int RING = 2 * (IMG_W + 2) + 2 * IMG_H;
    int nthr = NBATCH * RING;
    ConvKAN_corr<<<(nthr + 255) / 256, 256, 0, stream>>>(x, ws + WOFF_W1, rw, out);
}

// Round 9
// 153.887 us; speedup vs baseline: 1.6336x; 1.0251x over previous
//
#include <hip/hip_runtime.h>
#include <math.h>

#define IMG_H 512
#define IMG_W 512
#define NBATCH 8
#define TILE 32
#define GDIM 36            // TILE + 4 halo
#define NCH 9              // g channels: silu + 8 bases
#define NCONV 16
#define NPOS (GDIM * GDIM)

// ws layout (floats): [0,225) = Wc composed 5x5x9 kernel, [256, 256+1296) = W1 (16 x 9pos x 9ch)
#define WOFF_WC 0
#define WOFF_W1 256

typedef float f4 __attribute__((ext_vector_type(4)));
typedef _Float16 h8 __attribute__((ext_vector_type(8)));

// ---- g(x) = [silu(x), B0..B7(x)] : closed-form cubic B-spline bases on uniform
// grid t_j=(j-3)*0.4-1. u = x*2.5+5.5 maps knots to integers; i=floor(u), t=u-i.
__device__ __forceinline__ void eval_gb(float x, float& sl, float bj[8]) {
    float u = fmaf(x, 2.5f, 5.5f);
    float fi = floorf(u);
    int i = (int)fi;
    float t = u - fi;
    float s1 = 1.f - t;
    float t2 = t * t, t3 = t2 * t;
    float w0 = s1 * s1 * s1 * (1.f / 6.f);
    float w3 = t3 * (1.f / 6.f);
    float w1v = fmaf(0.5f, t3, 2.f / 3.f) - t2;          // (3t^3-6t^2+4)/6
    float msk = (u >= 0.f && u < 11.f) ? 1.f : 0.f;      // outside grid -> all bases 0
    w0 *= msk; w1v *= msk; w3 *= msk;
    float w2v = msk - w0 - w1v - w3;                     // partition of unity
    sl = x / (1.f + __expf(-x));                         // silu
#pragma unroll
    for (int j = 0; j < 8; ++j) {
        float v = 0.f;
        v = (i == j)     ? w3  : v;
        v = (i == j + 1) ? w2v : v;
        v = (i == j + 2) ? w1v : v;
        v = (i == j + 3) ? w0  : v;
        bj[j] = v;
    }
}

__device__ __forceinline__ void eval_g(float x, float g[NCH]) {
    float sl, bj[8];
    eval_gb(x, sl, bj);
    g[0] = sl;
#pragma unroll
    for (int j = 0; j < 8; ++j) g[j + 1] = bj[j];
}

// ---- prep: build W1 (KAN conv weights over g-channels) and composed 5x5 kernel Wc
__global__ void ConvKAN_prep(const float* __restrict__ bw, const float* __restrict__ sw,
                             const float* __restrict__ ss, const float* __restrict__ rw,
                             float* __restrict__ ws) {
    int t = threadIdx.x;
    // W1[(c*9 + i)*9 + ch], i = ky*3+kx
    for (int idx = t; idx < NCONV * 9 * NCH; idx += 256) {
        int ci = idx / NCH;      // c*9 + i
        int ch = idx % NCH;
        ws[WOFF_W1 + idx] = (ch == 0) ? bw[ci] : sw[ci * 8 + (ch - 1)] * ss[ci];
    }
    // Wc[(d*5+e)*9 + ch] = sum_c sum_{u,v} rw[c,u,v] * W1[c,ch,d-u,e-v]
    for (int idx = t; idx < 25 * NCH; idx += 256) {
        int de = idx / NCH, ch = idx % NCH;
        int d = de / 5, e = de % 5;
        float s = 0.0f;
        for (int c = 0; c < NCONV; ++c) {
            int ulo = d - 2 > 0 ? d - 2 : 0, uhi = d < 2 ? d : 2;
            int vlo = e - 2 > 0 ? e - 2 : 0, vhi = e < 2 ? e : 2;
            for (int u = ulo; u <= uhi; ++u)
                for (int v = vlo; v <= vhi; ++v) {
                    int i = (d - u) * 3 + (e - v);
                    float w1v = (ch == 0) ? bw[c * 9 + i]
                                          : sw[(c * 9 + i) * 8 + (ch - 1)] * ss[c * 9 + i];
                    s += rw[c * 9 + u * 3 + v] * w1v;
                }
        }
        ws[WOFF_WC + idx] = s;
    }
}

// ---- main: round-8 structure; ONE change: bases stored f16 (h8, one b128/tap),
// silu stays f32. Mixed-precision FMA (v_fma_mix) consumes f16 directly.
__global__ __launch_bounds__(256) void ConvKAN_main(const float* __restrict__ x,
                                                    const float* __restrict__ wc,
                                                    const float* __restrict__ rb,
                                                    float* __restrict__ out) {
    __shared__ h8 HB[NPOS];       // bases 0..7 as f16x8 (16B)
    __shared__ float SS[NPOS];    // silu (f32)
    int tid = threadIdx.x;
    int b = blockIdx.z;
    int y0 = blockIdx.y * TILE, x0 = blockIdx.x * TILE;
    const float* xb = x + (size_t)b * IMG_H * IMG_W;

    for (int i = tid; i < NPOS; i += 256) {
        int r = i / GDIM, c = i % GDIM;
        int gy = y0 + r - 2, gx = x0 + c - 2;
        float xv = (gy >= 0 && gy < IMG_H && gx >= 0 && gx < IMG_W) ? xb[gy * IMG_W + gx] : 0.0f;
        float sl, bj[8];
        eval_gb(xv, sl, bj);   // OOB -> g(0): matches zero-padded im2col semantics
        h8 hv;
#pragma unroll
        for (int j = 0; j < 8; ++j) hv[j] = (_Float16)bj[j];
        HB[i] = hv; SS[i] = sl;
    }
    __syncthreads();

    int tx = tid & 31;
    int ty = tid >> 5;          // 0..7
    int r0 = ty * 4;            // first output row (tile coords) of this thread
    float bias = rb[0];
    float acc[4] = {bias, bias, bias, bias};

#pragma unroll
    for (int R = 0; R < 8; ++R) {       // g rows r0+R cover rows needed by pixels p=0..3
#pragma unroll
        for (int e = 0; e < 5; ++e) {
            int pos = (r0 + R) * GDIM + tx + e;
            h8 hv = HB[pos]; float sl = SS[pos];
#pragma unroll
            for (int p = 0; p < 4; ++p) {
                int d = R - p;
                if (d < 0 || d > 4) continue;          // compile-time eliminated
                const float* wp = &wc[(d * 5 + e) * NCH];
                float a0 = fmaf(sl, wp[0], acc[p]);
                a0 = fmaf((float)hv[0], wp[1], a0); a0 = fmaf((float)hv[1], wp[2], a0);
                a0 = fmaf((float)hv[2], wp[3], a0); a0 = fmaf((float)hv[3], wp[4], a0);
                a0 = fmaf((float)hv[4], wp[5], a0); a0 = fmaf((float)hv[5], wp[6], a0);
                a0 = fmaf((float)hv[6], wp[7], a0); a0 = fmaf((float)hv[7], wp[8], a0);
                acc[p] = a0;
            }
        }
    }
    float* ob = out + ((size_t)b * IMG_H + y0) * IMG_W + x0;
#pragma unroll
    for (int p = 0; p < 4; ++p)
        ob[(r0 + p) * IMG_W + tx] = acc[p];
}

// ---- border correction: subtract contributions of "virtual feat" at the 1-ring outside image
__global__ void ConvKAN_corr(const float* __restrict__ x, const float* __restrict__ w1,
                             const float* __restrict__ rw, float* __restrict__ out) {
    int t = blockIdx.x * 256 + threadIdx.x;
    const int RING = 2 * (IMG_W + 2) + 2 * IMG_H;  // 2052
    if (t >= NBATCH * RING) return;
    int b = t / RING, r = t % RING;
    int fy, fx;
    if (r < IMG_W + 2)            { fy = -1;            fx = r - 1; }
    else if (r < 2 * (IMG_W + 2)) { fy = IMG_H;         fx = (r - (IMG_W + 2)) - 1; }
    else if (r < 2 * (IMG_W + 2) + IMG_H) { fy = r - 2 * (IMG_W + 2); fx = -1; }
    else                          { fy = r - (2 * (IMG_W + 2) + IMG_H); fx = IMG_W; }

    const float* xb = x + (size_t)b * IMG_H * IMG_W;
    float fc[NCONV];
#pragma unroll
    for (int c = 0; c < NCONV; ++c) fc[c] = 0.0f;

#pragma unroll
    for (int a = 0; a < 3; ++a) {
#pragma unroll
        for (int bb = 0; bb < 3; ++bb) {
            int gy = fy + a - 1, gx = fx + bb - 1;
            float xv = (gy >= 0 && gy < IMG_H && gx >= 0 && gx < IMG_W) ? xb[gy * IMG_W + gx] : 0.0f;
            float g[NCH];
            eval_g(xv, g);
            int i = a * 3 + bb;
#pragma unroll
            for (int c = 0; c < NCONV; ++c) {
                const float* wp = &w1[(c * 9 + i) * NCH];
                float s = 0.0f;
#pragma unroll
                for (int ch = 0; ch < NCH; ++ch) s += wp[ch] * g[ch];
                fc[c] += s;
            }
        }
    }
    // scatter: out(fy-u+1, fx-v+1) -= sum_c rw[c,u,v]*fc[c]
#pragma unroll
    for (int u = 0; u < 3; ++u) {
#pragma unroll
        for (int v = 0; v < 3; ++v) {
            int ty = fy - (u - 1), tx2 = fx - (v - 1);
            if (ty >= 0 && ty < IMG_H && tx2 >= 0 && tx2 < IMG_W) {
                float s = 0.0f;
#pragma unroll
                for (int c = 0; c < NCONV; ++c) s += rw[c * 9 + u * 3 + v] * fc[c];
                atomicAdd(&out[((size_t)b * IMG_H + ty) * IMG_W + tx2], -s);
            }
        }
    }
}

extern "C" void kernel_launch(void* const* d_in, const int* in_sizes, int n_in,
                              void* d_out, int out_size, void* d_ws, size_t ws_size,
                              hipStream_t stream) {
    const float* x  = (const float*)d_in[0];
    const float* bw = (const float*)d_in[1];
    const float* sw = (const float*)d_in[2];
    const float* ss = (const float*)d_in[3];
    const float* rw = (const float*)d_in[4];
    const float* rb = (const float*)d_in[5];
    float* out = (float*)d_out;
    float* ws  = (float*)d_ws;

    ConvKAN_prep<<<1, 256, 0, stream>>>(bw, sw, ss, rw, ws);
    ConvKAN_main<<<dim3(IMG_W / TILE, IMG_H / TILE, NBATCH), 256, 0, stream>>>(
        x, ws + WOFF_WC, rb, out);
    const int RING = 2 * (IMG_W + 2) + 2 * IMG_H;
    int nthr = NBATCH * RING;
    ConvKAN_corr<<<(nthr + 255) / 256, 256, 0, stream>>>(x, ws + WOFF_W1, rw, out);
}

// Round 10
// 150.815 us; speedup vs baseline: 1.6669x; 1.0204x over previous
//
#include <hip/hip_runtime.h>
#include <math.h>

#define IMG_H 512
#define IMG_W 512
#define NBATCH 8
#define TILE 32
#define GDIM 36            // TILE + 4 halo
#define NCH 9              // g channels: silu + 8 bases
#define NCONV 16
#define NPOS (GDIM * GDIM)

// ws layout (floats): [0,100) = WCH (25 taps x 8 f16 bases-weights, as h8),
// [128,153) = WCS (25 f32 silu-weights), [256, 256+1296) = W1 (16 x 9pos x 9ch)
#define WOFF_WCH 0
#define WOFF_WCS 128
#define WOFF_W1 256

typedef _Float16 h2 __attribute__((ext_vector_type(2)));
typedef _Float16 h8 __attribute__((ext_vector_type(8)));

// ---- g(x) = [silu(x), B0..B7(x)] : closed-form cubic B-spline bases on uniform
// grid t_j=(j-3)*0.4-1. u = x*2.5+5.5 maps knots to integers; i=floor(u), t=u-i.
__device__ __forceinline__ void eval_gb(float x, float& sl, float bj[8]) {
    float u = fmaf(x, 2.5f, 5.5f);
    float fi = floorf(u);
    int i = (int)fi;
    float t = u - fi;
    float s1 = 1.f - t;
    float t2 = t * t, t3 = t2 * t;
    float w0 = s1 * s1 * s1 * (1.f / 6.f);
    float w3 = t3 * (1.f / 6.f);
    float w1v = fmaf(0.5f, t3, 2.f / 3.f) - t2;          // (3t^3-6t^2+4)/6
    float msk = (u >= 0.f && u < 11.f) ? 1.f : 0.f;      // outside grid -> all bases 0
    w0 *= msk; w1v *= msk; w3 *= msk;
    float w2v = msk - w0 - w1v - w3;                     // partition of unity
    sl = x / (1.f + __expf(-x));                         // silu
#pragma unroll
    for (int j = 0; j < 8; ++j) {
        float v = 0.f;
        v = (i == j)     ? w3  : v;
        v = (i == j + 1) ? w2v : v;
        v = (i == j + 2) ? w1v : v;
        v = (i == j + 3) ? w0  : v;
        bj[j] = v;
    }
}

__device__ __forceinline__ void eval_g(float x, float g[NCH]) {
    float sl, bj[8];
    eval_gb(x, sl, bj);
    g[0] = sl;
#pragma unroll
    for (int j = 0; j < 8; ++j) g[j + 1] = bj[j];
}

// ---- prep: W1 (f32), composed 5x5 kernel packed as f16 (bases) + f32 (silu)
__global__ void ConvKAN_prep(const float* __restrict__ bw, const float* __restrict__ sw,
                             const float* __restrict__ ss, const float* __restrict__ rw,
                             float* __restrict__ ws) {
    __shared__ float WC[225];
    int t = threadIdx.x;
    // W1[(c*9 + i)*9 + ch], i = ky*3+kx  (f32, used by corr kernel)
    for (int idx = t; idx < NCONV * 9 * NCH; idx += 256) {
        int ci = idx / NCH;
        int ch = idx % NCH;
        ws[WOFF_W1 + idx] = (ch == 0) ? bw[ci] : sw[ci * 8 + (ch - 1)] * ss[ci];
    }
    // Wc[(d*5+e)*9 + ch] = sum_c sum_{u,v} rw[c,u,v] * W1[c,ch,d-u,e-v]
    if (t < 225) {
        int de = t / NCH, ch = t % NCH;
        int d = de / 5, e = de % 5;
        float s = 0.0f;
        for (int c = 0; c < NCONV; ++c) {
            int ulo = d - 2 > 0 ? d - 2 : 0, uhi = d < 2 ? d : 2;
            int vlo = e - 2 > 0 ? e - 2 : 0, vhi = e < 2 ? e : 2;
            for (int u = ulo; u <= uhi; ++u)
                for (int v = vlo; v <= vhi; ++v) {
                    int i = (d - u) * 3 + (e - v);
                    float w1v = (ch == 0) ? bw[c * 9 + i]
                                          : sw[(c * 9 + i) * 8 + (ch - 1)] * ss[c * 9 + i];
                    s += rw[c * 9 + u * 3 + v] * w1v;
                }
        }
        WC[t] = s;
    }
    __syncthreads();
    if (t < 25) {
        h8 hw;
#pragma unroll
        for (int j = 0; j < 8; ++j) hw[j] = (_Float16)WC[t * 9 + 1 + j];
        ((h8*)(ws + WOFF_WCH))[t] = hw;
        ws[WOFF_WCS + t] = WC[t * 9];
    }
}

// ---- main: r9 structure; ONE change: f16 weights + v_dot2_f32_f16 (fdot2)
// hot body = 1 f32 fma (silu) + 4 fdot2 instead of 9 fma_mix.
__global__ __launch_bounds__(256) void ConvKAN_main(const float* __restrict__ x,
                                                    const float* __restrict__ wpack,
                                                    const float* __restrict__ wsl,
                                                    const float* __restrict__ rb,
                                                    float* __restrict__ out) {
    __shared__ h8 HB[NPOS];       // bases 0..7 as f16x8 (16B)
    __shared__ float SS[NPOS];    // silu (f32)
    int tid = threadIdx.x;
    int b = blockIdx.z;
    int y0 = blockIdx.y * TILE, x0 = blockIdx.x * TILE;
    const float* xb = x + (size_t)b * IMG_H * IMG_W;

    for (int i = tid; i < NPOS; i += 256) {
        int r = i / GDIM, c = i % GDIM;
        int gy = y0 + r - 2, gx = x0 + c - 2;
        float xv = (gy >= 0 && gy < IMG_H && gx >= 0 && gx < IMG_W) ? xb[gy * IMG_W + gx] : 0.0f;
        float sl, bj[8];
        eval_gb(xv, sl, bj);   // OOB -> g(0): matches zero-padded im2col semantics
        h8 hv;
#pragma unroll
        for (int j = 0; j < 8; ++j) hv[j] = (_Float16)bj[j];
        HB[i] = hv; SS[i] = sl;
    }
    __syncthreads();

    int tx = tid & 31;
    int ty = tid >> 5;          // 0..7
    int r0 = ty * 4;            // first output row (tile coords) of this thread
    float bias = rb[0];
    float acc[4] = {bias, bias, bias, bias};

#pragma unroll
    for (int R = 0; R < 8; ++R) {       // g rows r0+R cover rows needed by pixels p=0..3
#pragma unroll
        for (int e = 0; e < 5; ++e) {
            int pos = (r0 + R) * GDIM + tx + e;
            h8 hv = HB[pos]; float sl = SS[pos];
            h2 b0 = {hv[0], hv[1]}, b1 = {hv[2], hv[3]};
            h2 b2 = {hv[4], hv[5]}, b3 = {hv[6], hv[7]};
#pragma unroll
            for (int p = 0; p < 4; ++p) {
                int d = R - p;
                if (d < 0 || d > 4) continue;          // compile-time eliminated
                int t = d * 5 + e;
                const h2* wh = (const h2*)&wpack[t * 4];   // 8 f16 = 4 floats per tap
                float a0 = fmaf(sl, wsl[t], acc[p]);
                a0 = __builtin_amdgcn_fdot2(b0, wh[0], a0, false);
                a0 = __builtin_amdgcn_fdot2(b1, wh[1], a0, false);
                a0 = __builtin_amdgcn_fdot2(b2, wh[2], a0, false);
                a0 = __builtin_amdgcn_fdot2(b3, wh[3], a0, false);
                acc[p] = a0;
            }
        }
    }
    float* ob = out + ((size_t)b * IMG_H + y0) * IMG_W + x0;
#pragma unroll
    for (int p = 0; p < 4; ++p)
        ob[(r0 + p) * IMG_W + tx] = acc[p];
}

// ---- border correction: subtract contributions of "virtual feat" at the 1-ring outside image
__global__ void ConvKAN_corr(const float* __restrict__ x, const float* __restrict__ w1,
                             const float* __restrict__ rw, float* __restrict__ out) {
    int t = blockIdx.x * 256 + threadIdx.x;
    const int RING = 2 * (IMG_W + 2) + 2 * IMG_H;  // 2052
    if (t >= NBATCH * RING) return;
    int b = t / RING, r = t % RING;
    int fy, fx;
    if (r < IMG_W + 2)            { fy = -1;            fx = r - 1; }
    else if (r < 2 * (IMG_W + 2)) { fy = IMG_H;         fx = (r - (IMG_W + 2)) - 1; }
    else if (r < 2 * (IMG_W + 2) + IMG_H) { fy = r - 2 * (IMG_W + 2); fx = -1; }
    else                          { fy = r - (2 * (IMG_W + 2) + IMG_H); fx = IMG_W; }

    const float* xb = x + (size_t)b * IMG_H * IMG_W;
    float fc[NCONV];
#pragma unroll
    for (int c = 0; c < NCONV; ++c) fc[c] = 0.0f;

#pragma unroll
    for (int a = 0; a < 3; ++a) {
#pragma unroll
        for (int bb = 0; bb < 3; ++bb) {
            int gy = fy + a - 1, gx = fx + bb - 1;
            float xv = (gy >= 0 && gy < IMG_H && gx >= 0 && gx < IMG_W) ? xb[gy * IMG_W + gx] : 0.0f;
            float g[NCH];
            eval_g(xv, g);
            int i = a * 3 + bb;
#pragma unroll
            for (int c = 0; c < NCONV; ++c) {
                const float* wp = &w1[(c * 9 + i) * NCH];
                float s = 0.0f;
#pragma unroll
                for (int ch = 0; ch < NCH; ++ch) s += wp[ch] * g[ch];
                fc[c] += s;
            }
        }
    }
    // scatter: out(fy-u+1, fx-v+1) -= sum_c rw[c,u,v]*fc[c]
#pragma unroll
    for (int u = 0; u < 3; ++u) {
#pragma unroll
        for (int v = 0; v < 3; ++v) {
            int ty = fy - (u - 1), tx2 = fx - (v - 1);
            if (ty >= 0 && ty < IMG_H && tx2 >= 0 && tx2 < IMG_W) {
                float s = 0.0f;
#pragma unroll
                for (int c = 0; c < NCONV; ++c) s += rw[c * 9 + u * 3 + v] * fc[c];
                atomicAdd(&out[((size_t)b * IMG_H + ty) * IMG_W + tx2], -s);
            }
        }
    }
}

extern "C" void kernel_launch(void* const* d_in, const int* in_sizes, int n_in,
                              void* d_out, int out_size, void* d_ws, size_t ws_size,
                              hipStream_t stream) {
    const float* x  = (const float*)d_in[0];
    const float* bw = (const float*)d_in[1];
    const float* sw = (const float*)d_in[2];
    const float* ss = (const float*)d_in[3];
    const float* rw = (const float*)d_in[4];
    const float* rb = (const float*)d_in[5];
    float* out = (float*)d_out;
    float* ws  = (float*)d_ws;

    ConvKAN_prep<<<1, 256, 0, stream>>>(bw, sw, ss, rw, ws);
    ConvKAN_main<<<dim3(IMG_W / TILE, IMG_H / TILE, NBATCH), 256, 0, stream>>>(
        x, ws + WOFF_WCH, ws + WOFF_WCS, rb, out);
    const int RING = 2 * (IMG_W + 2) + 2 * IMG_H;
    int nthr = NBATCH * RING;
    ConvKAN_corr<<<(nthr + 255) / 256, 256, 0, stream>>>(x, ws + WOFF_W1, rw, out);
}

// Round 11
// 125.911 us; speedup vs baseline: 1.9966x; 1.1978x over previous
//
#include <hip/hip_runtime.h>
#include <math.h>

#define IMG_H 512
#define IMG_W 512
#define NBATCH 8
#define TILE 32
#define GDIM 36            // TILE + 4 halo
#define NCH 9              // g channels: silu + 8 bases
#define NCONV 16
#define NPOS (GDIM * GDIM)
#define RINGN (2 * (IMG_W + 2) + 2 * IMG_H)   // 2052
#define CPB 16             // corr positions per block

// ws layout (floats): [0,100) = WCH (25 taps x 8 f16 bases-weights, as h8),
// [128,153) = WCS (25 f32 silu-weights), [256, 256+1296) = W1 (16 x 9pos x 9ch)
#define WOFF_WCH 0
#define WOFF_WCS 128
#define WOFF_W1 256

typedef _Float16 h2 __attribute__((ext_vector_type(2)));
typedef _Float16 h8 __attribute__((ext_vector_type(8)));

// ---- g(x) = [silu(x), B0..B7(x)] : closed-form cubic B-spline bases on uniform
// grid t_j=(j-3)*0.4-1. u = x*2.5+5.5 maps knots to integers; i=floor(u), t=u-i.
__device__ __forceinline__ void eval_gb(float x, float& sl, float bj[8]) {
    float u = fmaf(x, 2.5f, 5.5f);
    float fi = floorf(u);
    int i = (int)fi;
    float t = u - fi;
    float s1 = 1.f - t;
    float t2 = t * t, t3 = t2 * t;
    float w0 = s1 * s1 * s1 * (1.f / 6.f);
    float w3 = t3 * (1.f / 6.f);
    float w1v = fmaf(0.5f, t3, 2.f / 3.f) - t2;          // (3t^3-6t^2+4)/6
    float msk = (u >= 0.f && u < 11.f) ? 1.f : 0.f;      // outside grid -> all bases 0
    w0 *= msk; w1v *= msk; w3 *= msk;
    float w2v = msk - w0 - w1v - w3;                     // partition of unity
    sl = x / (1.f + __expf(-x));                         // silu
#pragma unroll
    for (int j = 0; j < 8; ++j) {
        float v = 0.f;
        v = (i == j)     ? w3  : v;
        v = (i == j + 1) ? w2v : v;
        v = (i == j + 2) ? w1v : v;
        v = (i == j + 3) ? w0  : v;
        bj[j] = v;
    }
}

__device__ __forceinline__ void eval_g(float x, float g[NCH]) {
    float sl, bj[8];
    eval_gb(x, sl, bj);
    g[0] = sl;
#pragma unroll
    for (int j = 0; j < 8; ++j) g[j + 1] = bj[j];
}

// ring index r -> virtual feat coords (fy, fx), 1-ring outside the image
__device__ __forceinline__ void ring2fyfx(int r, int& fy, int& fx) {
    if (r < IMG_W + 2)            { fy = -1;    fx = r - 1; }
    else if (r < 2 * (IMG_W + 2)) { fy = IMG_H; fx = (r - (IMG_W + 2)) - 1; }
    else if (r < 2 * (IMG_W + 2) + IMG_H) { fy = r - 2 * (IMG_W + 2); fx = -1; }
    else                          { fy = r - (2 * (IMG_W + 2) + IMG_H); fx = IMG_W; }
}

// ---- prep: W1 (f32), composed 5x5 kernel packed as f16 (bases) + f32 (silu)
__global__ void ConvKAN_prep(const float* __restrict__ bw, const float* __restrict__ sw,
                             const float* __restrict__ ss, const float* __restrict__ rw,
                             float* __restrict__ ws) {
    __shared__ float WC[225];
    int t = threadIdx.x;
    // W1[(c*9 + i)*9 + ch], i = ky*3+kx  (f32, used by corr kernel)
    for (int idx = t; idx < NCONV * 9 * NCH; idx += 256) {
        int ci = idx / NCH;
        int ch = idx % NCH;
        ws[WOFF_W1 + idx] = (ch == 0) ? bw[ci] : sw[ci * 8 + (ch - 1)] * ss[ci];
    }
    // Wc[(d*5+e)*9 + ch] = sum_c sum_{u,v} rw[c,u,v] * W1[c,ch,d-u,e-v]
    if (t < 225) {
        int de = t / NCH, ch = t % NCH;
        int d = de / 5, e = de % 5;
        float s = 0.0f;
        for (int c = 0; c < NCONV; ++c) {
            int ulo = d - 2 > 0 ? d - 2 : 0, uhi = d < 2 ? d : 2;
            int vlo = e - 2 > 0 ? e - 2 : 0, vhi = e < 2 ? e : 2;
            for (int u = ulo; u <= uhi; ++u)
                for (int v = vlo; v <= vhi; ++v) {
                    int i = (d - u) * 3 + (e - v);
                    float w1v = (ch == 0) ? bw[c * 9 + i]
                                          : sw[(c * 9 + i) * 8 + (ch - 1)] * ss[c * 9 + i];
                    s += rw[c * 9 + u * 3 + v] * w1v;
                }
        }
        WC[t] = s;
    }
    __syncthreads();
    if (t < 25) {
        h8 hw;
#pragma unroll
        for (int j = 0; j < 8; ++j) hw[j] = (_Float16)WC[t * 9 + 1 + j];
        ((h8*)(ws + WOFF_WCH))[t] = hw;
        ws[WOFF_WCS + t] = WC[t * 9];
    }
}

// ---- main: unchanged from r10 (f16 bases in LDS, f16 weights, fdot2 hot loop)
__global__ __launch_bounds__(256) void ConvKAN_main(const float* __restrict__ x,
                                                    const float* __restrict__ wpack,
                                                    const float* __restrict__ wsl,
                                                    const float* __restrict__ rb,
                                                    float* __restrict__ out) {
    __shared__ h8 HB[NPOS];       // bases 0..7 as f16x8 (16B)
    __shared__ float SS[NPOS];    // silu (f32)
    int tid = threadIdx.x;
    int b = blockIdx.z;
    int y0 = blockIdx.y * TILE, x0 = blockIdx.x * TILE;
    const float* xb = x + (size_t)b * IMG_H * IMG_W;

    for (int i = tid; i < NPOS; i += 256) {
        int r = i / GDIM, c = i % GDIM;
        int gy = y0 + r - 2, gx = x0 + c - 2;
        float xv = (gy >= 0 && gy < IMG_H && gx >= 0 && gx < IMG_W) ? xb[gy * IMG_W + gx] : 0.0f;
        float sl, bj[8];
        eval_gb(xv, sl, bj);   // OOB -> g(0): matches zero-padded im2col semantics
        h8 hv;
#pragma unroll
        for (int j = 0; j < 8; ++j) hv[j] = (_Float16)bj[j];
        HB[i] = hv; SS[i] = sl;
    }
    __syncthreads();

    int tx = tid & 31;
    int ty = tid >> 5;          // 0..7
    int r0 = ty * 4;            // first output row (tile coords) of this thread
    float bias = rb[0];
    float acc[4] = {bias, bias, bias, bias};

#pragma unroll
    for (int R = 0; R < 8; ++R) {       // g rows r0+R cover rows needed by pixels p=0..3
#pragma unroll
        for (int e = 0; e < 5; ++e) {
            int pos = (r0 + R) * GDIM + tx + e;
            h8 hv = HB[pos]; float sl = SS[pos];
            h2 b0 = {hv[0], hv[1]}, b1 = {hv[2], hv[3]};
            h2 b2 = {hv[4], hv[5]}, b3 = {hv[6], hv[7]};
#pragma unroll
            for (int p = 0; p < 4; ++p) {
                int d = R - p;
                if (d < 0 || d > 4) continue;          // compile-time eliminated
                int t = d * 5 + e;
                const h2* wh = (const h2*)&wpack[t * 4];   // 8 f16 = 4 floats per tap
                float a0 = fmaf(sl, wsl[t], acc[p]);
                a0 = __builtin_amdgcn_fdot2(b0, wh[0], a0, false);
                a0 = __builtin_amdgcn_fdot2(b1, wh[1], a0, false);
                a0 = __builtin_amdgcn_fdot2(b2, wh[2], a0, false);
                a0 = __builtin_amdgcn_fdot2(b3, wh[3], a0, false);
                acc[p] = a0;
            }
        }
    }
    float* ob = out + ((size_t)b * IMG_H + y0) * IMG_W + x0;
#pragma unroll
    for (int p = 0; p < 4; ++p)
        ob[(r0 + p) * IMG_W + tx] = acc[p];
}

// ---- border correction v2: block = 16 positions x 16 convs (1026 blocks).
// w1 + per-position g staged in LDS; one fc per thread; shfl_xor reduce over c;
// lane c==0 issues the atomic. Was: 65 blocks, 1296 global loads/thread, 70us.
__global__ __launch_bounds__(256) void ConvKAN_corr(const float* __restrict__ x,
        const float* __restrict__ w1, const float* __restrict__ rw,
        float* __restrict__ out) {
    __shared__ float LW[NCONV * 81];   // w1[c][i][ch], 5184 B
    __shared__ float G[CPB * 81];      // g[pos_local][tap][ch], 5184 B

    int tid = threadIdx.x;
    for (int idx = tid; idx < NCONV * 81; idx += 256) LW[idx] = w1[idx];

    if (tid < CPB * 9) {
        int pl = tid / 9, tap = tid % 9;
        int pg = blockIdx.x * CPB + pl;
        int b = pg / RINGN, r = pg % RINGN;
        int fy, fx;
        ring2fyfx(r, fy, fx);
        int a = tap / 3, bb = tap % 3;
        int gy = fy + a - 1, gx = fx + bb - 1;
        const float* xb = x + (size_t)b * IMG_H * IMG_W;
        float xv = (gy >= 0 && gy < IMG_H && gx >= 0 && gx < IMG_W) ? xb[gy * IMG_W + gx] : 0.f;
        float g[NCH];
        eval_g(xv, g);
#pragma unroll
        for (int ch = 0; ch < NCH; ++ch) G[pl * 81 + tap * 9 + ch] = g[ch];
    }
    __syncthreads();

    int pl = tid >> 4, c = tid & 15;
    int pg = blockIdx.x * CPB + pl;
    int b = pg / RINGN, r = pg % RINGN;
    int fy, fx;
    ring2fyfx(r, fy, fx);

    float fc = 0.f;
#pragma unroll
    for (int i = 0; i < 9; ++i)
#pragma unroll
        for (int ch = 0; ch < 9; ++ch)
            fc = fmaf(LW[c * 81 + i * 9 + ch], G[pl * 81 + i * 9 + ch], fc);

#pragma unroll
    for (int dd = 0; dd < 9; ++dd) {
        int u = dd / 3, v = dd % 3;
        int ty = fy - (u - 1), tx2 = fx - (v - 1);
        if (ty >= 0 && ty < IMG_H && tx2 >= 0 && tx2 < IMG_W) {   // uniform per 16-lane group
            float s = rw[c * 9 + dd] * fc;
            s += __shfl_xor(s, 1);
            s += __shfl_xor(s, 2);
            s += __shfl_xor(s, 4);
            s += __shfl_xor(s, 8);
            if (c == 0)
                atomicAdd(&out[((size_t)b * IMG_H + ty) * IMG_W + tx2], -s);
        }
    }
}

extern "C" void kernel_launch(void* const* d_in, const int* in_sizes, int n_in,
                              void* d_out, int out_size, void* d_ws, size_t ws_size,
                              hipStream_t stream) {
    const float* x  = (const float*)d_in[0];
    const float* bw = (const float*)d_in[1];
    const float* sw = (const float*)d_in[2];
    const float* ss = (const float*)d_in[3];
    const float* rw = (const float*)d_in[4];
    const float* rb = (const float*)d_in[5];
    float* out = (float*)d_out;
    float* ws  = (float*)d_ws;

    ConvKAN_prep<<<1, 256, 0, stream>>>(bw, sw, ss, rw, ws);
    ConvKAN_main<<<dim3(IMG_W / TILE, IMG_H / TILE, NBATCH), 256, 0, stream>>>(
        x, ws + WOFF_WCH, ws + WOFF_WCS, rb, out);
    int nblk = (NBATCH * RINGN) / CPB;   // 16416 / 16 = 1026 exactly
    ConvKAN_corr<<<nblk, 256, 0, stream>>>(x, ws + WOFF_W1, rw, out);
}

// Round 12
// 125.285 us; speedup vs baseline: 2.0066x; 1.0050x over previous
//
#include <hip/hip_runtime.h>
#include <math.h>

#define IMG_H 512
#define IMG_W 512
#define NBATCH 8
#define TILE 32
#define GDIM 36            // TILE + 4 halo
#define NCH 9              // g channels: silu + 8 bases
#define NCONV 16
#define NPOS (GDIM * GDIM)
#define NBORD (2 * IMG_W + 2 * (IMG_H - 2))   // 2044 border pixels per image

// ws layout (floats): [0,100) = WCH (25 taps x 8 f16 bases-weights, as h8),
// [128,153) = WCS (25 f32 silu-weights), [256,985) = WV (9 uv x 9 tap x 9 ch)
#define WOFF_WCH 0
#define WOFF_WCS 128
#define WOFF_WV  256

typedef _Float16 h2 __attribute__((ext_vector_type(2)));
typedef _Float16 h8 __attribute__((ext_vector_type(8)));

// ---- g(x) = [silu(x), B0..B7(x)] : closed-form cubic B-spline bases on uniform
// grid t_j=(j-3)*0.4-1. u = x*2.5+5.5 maps knots to integers; i=floor(u), t=u-i.
__device__ __forceinline__ void eval_gb(float x, float& sl, float bj[8]) {
    float u = fmaf(x, 2.5f, 5.5f);
    float fi = floorf(u);
    int i = (int)fi;
    float t = u - fi;
    float s1 = 1.f - t;
    float t2 = t * t, t3 = t2 * t;
    float w0 = s1 * s1 * s1 * (1.f / 6.f);
    float w3 = t3 * (1.f / 6.f);
    float w1v = fmaf(0.5f, t3, 2.f / 3.f) - t2;          // (3t^3-6t^2+4)/6
    float msk = (u >= 0.f && u < 11.f) ? 1.f : 0.f;      // outside grid -> all bases 0
    w0 *= msk; w1v *= msk; w3 *= msk;
    float w2v = msk - w0 - w1v - w3;                     // partition of unity
    sl = x / (1.f + __expf(-x));                         // silu
#pragma unroll
    for (int j = 0; j < 8; ++j) {
        float v = 0.f;
        v = (i == j)     ? w3  : v;
        v = (i == j + 1) ? w2v : v;
        v = (i == j + 2) ? w1v : v;
        v = (i == j + 3) ? w0  : v;
        bj[j] = v;
    }
}

__device__ __forceinline__ void eval_g(float x, float g[NCH]) {
    float sl, bj[8];
    eval_gb(x, sl, bj);
    g[0] = sl;
#pragma unroll
    for (int j = 0; j < 8; ++j) g[j + 1] = bj[j];
}

// ---- prep: composed 5x5 kernel (f16 bases + f32 silu) and border-fold weights
// WV[uv][tap][ch] = sum_c rw[c,uv] * W1[c,tap,ch]
__global__ void ConvKAN_prep(const float* __restrict__ bw, const float* __restrict__ sw,
                             const float* __restrict__ ss, const float* __restrict__ rw,
                             float* __restrict__ ws) {
    __shared__ float W1s[NCONV * 81];
    __shared__ float WC[225];
    int t = threadIdx.x;
    for (int idx = t; idx < NCONV * 81; idx += 256) {
        int ci = idx / NCH;
        int ch = idx % NCH;
        W1s[idx] = (ch == 0) ? bw[ci] : sw[ci * 8 + (ch - 1)] * ss[ci];
    }
    __syncthreads();
    // Wc[(d*5+e)*9 + ch] = sum_c sum_{u,v} rw[c,u,v] * W1[c,ch,d-u,e-v]
    if (t < 225) {
        int de = t / NCH, ch = t % NCH;
        int d = de / 5, e = de % 5;
        float s = 0.0f;
        for (int c = 0; c < NCONV; ++c) {
            int ulo = d - 2 > 0 ? d - 2 : 0, uhi = d < 2 ? d : 2;
            int vlo = e - 2 > 0 ? e - 2 : 0, vhi = e < 2 ? e : 2;
            for (int u = ulo; u <= uhi; ++u)
                for (int v = vlo; v <= vhi; ++v) {
                    int i = (d - u) * 3 + (e - v);
                    s += rw[c * 9 + u * 3 + v] * W1s[(c * 9 + i) * NCH + ch];
                }
        }
        WC[t] = s;
    }
    // WV for border gather
    for (int idx = t; idx < 729; idx += 256) {
        int uv = idx / 81, rest = idx % 81;
        float s = 0.f;
        for (int c = 0; c < NCONV; ++c)
            s += rw[c * 9 + uv] * W1s[c * 81 + rest];
        ws[WOFF_WV + idx] = s;
    }
    __syncthreads();
    if (t < 25) {
        h8 hw;
#pragma unroll
        for (int j = 0; j < 8; ++j) hw[j] = (_Float16)WC[t * 9 + 1 + j];
        ((h8*)(ws + WOFF_WCH))[t] = hw;
        ws[WOFF_WCS + t] = WC[t * 9];
    }
}

// ---- main: unchanged from r10/r11 (f16 bases in LDS, f16 weights, fdot2 hot loop)
__global__ __launch_bounds__(256) void ConvKAN_main(const float* __restrict__ x,
                                                    const float* __restrict__ wpack,
                                                    const float* __restrict__ wsl,
                                                    const float* __restrict__ rb,
                                                    float* __restrict__ out) {
    __shared__ h8 HB[NPOS];       // bases 0..7 as f16x8 (16B)
    __shared__ float SS[NPOS];    // silu (f32)
    int tid = threadIdx.x;
    int b = blockIdx.z;
    int y0 = blockIdx.y * TILE, x0 = blockIdx.x * TILE;
    const float* xb = x + (size_t)b * IMG_H * IMG_W;

    for (int i = tid; i < NPOS; i += 256) {
        int r = i / GDIM, c = i % GDIM;
        int gy = y0 + r - 2, gx = x0 + c - 2;
        float xv = (gy >= 0 && gy < IMG_H && gx >= 0 && gx < IMG_W) ? xb[gy * IMG_W + gx] : 0.0f;
        float sl, bj[8];
        eval_gb(xv, sl, bj);   // OOB -> g(0): matches zero-padded im2col semantics
        h8 hv;
#pragma unroll
        for (int j = 0; j < 8; ++j) hv[j] = (_Float16)bj[j];
        HB[i] = hv; SS[i] = sl;
    }
    __syncthreads();

    int tx = tid & 31;
    int ty = tid >> 5;          // 0..7
    int r0 = ty * 4;            // first output row (tile coords) of this thread
    float bias = rb[0];
    float acc[4] = {bias, bias, bias, bias};

#pragma unroll
    for (int R = 0; R < 8; ++R) {       // g rows r0+R cover rows needed by pixels p=0..3
#pragma unroll
        for (int e = 0; e < 5; ++e) {
            int pos = (r0 + R) * GDIM + tx + e;
            h8 hv = HB[pos]; float sl = SS[pos];
            h2 b0 = {hv[0], hv[1]}, b1 = {hv[2], hv[3]};
            h2 b2 = {hv[4], hv[5]}, b3 = {hv[6], hv[7]};
#pragma unroll
            for (int p = 0; p < 4; ++p) {
                int d = R - p;
                if (d < 0 || d > 4) continue;          // compile-time eliminated
                int t = d * 5 + e;
                const h2* wh = (const h2*)&wpack[t * 4];   // 8 f16 = 4 floats per tap
                float a0 = fmaf(sl, wsl[t], acc[p]);
                a0 = __builtin_amdgcn_fdot2(b0, wh[0], a0, false);
                a0 = __builtin_amdgcn_fdot2(b1, wh[1], a0, false);
                a0 = __builtin_amdgcn_fdot2(b2, wh[2], a0, false);
                a0 = __builtin_amdgcn_fdot2(b3, wh[3], a0, false);
                acc[p] = a0;
            }
        }
    }
    float* ob = out + ((size_t)b * IMG_H + y0) * IMG_W + x0;
#pragma unroll
    for (int p = 0; p < 4; ++p)
        ob[(r0 + p) * IMG_W + tx] = acc[p];
}

// ---- border correction v3 (gather, atomic-free): one thread per border pixel.
// corr(y,x) = sum over OUTSIDE neighbors f=(y+du,x+dv) of
//             sum_tap sum_ch WV[(du+1)*3+dv+1][tap][ch] * g_ch(x[f+tap offset])
// Plain read-modify-write on out (each border pixel owned by exactly one thread).
__global__ __launch_bounds__(256) void ConvKAN_corr(const float* __restrict__ x,
        const float* __restrict__ wv, float* __restrict__ out) {
    __shared__ float WV[729];
    int tid = threadIdx.x;
    for (int idx = tid; idx < 729; idx += 256) WV[idx] = wv[idx];
    __syncthreads();

    int q = blockIdx.x * 256 + tid;
    if (q >= NBATCH * NBORD) return;
    int b = q / NBORD, r = q % NBORD;
    int y, xc;
    if (r < IMG_W)               { y = 0;             xc = r; }
    else if (r < 2 * IMG_W)      { y = IMG_H - 1;     xc = r - IMG_W; }
    else if (r < 2 * IMG_W + IMG_H - 2) { y = r - 2 * IMG_W + 1; xc = 0; }
    else                         { y = r - (2 * IMG_W + IMG_H - 2) + 1; xc = IMG_W - 1; }

    const float* xb = x + (size_t)b * IMG_H * IMG_W;
    float corr = 0.f;
#pragma unroll 1
    for (int uv = 0; uv < 9; ++uv) {
        int du = uv / 3 - 1, dv = uv % 3 - 1;
        int fy = y + du, fx = xc + dv;
        if (fy >= 0 && fy < IMG_H && fx >= 0 && fx < IMG_W) continue;  // inside: no correction
        const float* wvp = &WV[uv * 81];
#pragma unroll
        for (int tap = 0; tap < 9; ++tap) {
            int gy = fy + tap / 3 - 1, gx = fx + tap % 3 - 1;
            float xv = (gy >= 0 && gy < IMG_H && gx >= 0 && gx < IMG_W) ? xb[gy * IMG_W + gx] : 0.f;
            float g[NCH];
            eval_g(xv, g);
#pragma unroll
            for (int ch = 0; ch < NCH; ++ch)
                corr = fmaf(wvp[tap * 9 + ch], g[ch], corr);
        }
    }
    size_t oi = ((size_t)b * IMG_H + y) * IMG_W + xc;
    out[oi] = out[oi] - corr;
}

extern "C" void kernel_launch(void* const* d_in, const int* in_sizes, int n_in,
                              void* d_out, int out_size, void* d_ws, size_t ws_size,
                              hipStream_t stream) {
    const float* x  = (const float*)d_in[0];
    const float* bw = (const float*)d_in[1];
    const float* sw = (const float*)d_in[2];
    const float* ss = (const float*)d_in[3];
    const float* rw = (const float*)d_in[4];
    const float* rb = (const float*)d_in[5];
    float* out = (float*)d_out;
    float* ws  = (float*)d_ws;

    ConvKAN_prep<<<1, 256, 0, stream>>>(bw, sw, ss, rw, ws);
    ConvKAN_main<<<dim3(IMG_W / TILE, IMG_H / TILE, NBATCH), 256, 0, stream>>>(
        x, ws + WOFF_WCH, ws + WOFF_WCS, rb, out);
    int nthr = NBATCH * NBORD;               // 16352
    ConvKAN_corr<<<(nthr + 255) / 256, 256, 0, stream>>>(x, ws + WOFF_WV, out);
}

// Round 13
// 110.267 us; speedup vs baseline: 2.2798x; 1.1362x over previous
//
#include <hip/hip_runtime.h>
#include <math.h>

#define IMG_H 512
#define IMG_W 512
#define NBATCH 8
#define TILE 32
#define GDIM 36            // TILE + 4 halo
#define NCH 9              // g channels: silu + 8 bases
#define NCONV 16
#define NPOS (GDIM * GDIM)
#define NBORD (2 * IMG_W + 2 * (IMG_H - 2))   // 2044 border pixels per image
#define NPIX (NBATCH * NBORD)                 // 16352

// ws layout (floats): [0,100) = WCH (25 taps x 8 f16 bases-weights, as h8),
// [128,153) = WCS (25 f32 silu-weights), [256,985) = WV (9 uv x 9 tap x 9 ch)
#define WOFF_WCH 0
#define WOFF_WCS 128
#define WOFF_WV  256

typedef _Float16 h2 __attribute__((ext_vector_type(2)));
typedef _Float16 h8 __attribute__((ext_vector_type(8)));

// ---- g(x) = [silu(x), B0..B7(x)] : closed-form cubic B-spline bases on uniform
// grid t_j=(j-3)*0.4-1. u = x*2.5+5.5 maps knots to integers; i=floor(u), t=u-i.
__device__ __forceinline__ void eval_gb(float x, float& sl, float bj[8]) {
    float u = fmaf(x, 2.5f, 5.5f);
    float fi = floorf(u);
    int i = (int)fi;
    float t = u - fi;
    float s1 = 1.f - t;
    float t2 = t * t, t3 = t2 * t;
    float w0 = s1 * s1 * s1 * (1.f / 6.f);
    float w3 = t3 * (1.f / 6.f);
    float w1v = fmaf(0.5f, t3, 2.f / 3.f) - t2;          // (3t^3-6t^2+4)/6
    float msk = (u >= 0.f && u < 11.f) ? 1.f : 0.f;      // outside grid -> all bases 0
    w0 *= msk; w1v *= msk; w3 *= msk;
    float w2v = msk - w0 - w1v - w3;                     // partition of unity
    sl = x / (1.f + __expf(-x));                         // silu
#pragma unroll
    for (int j = 0; j < 8; ++j) {
        float v = 0.f;
        v = (i == j)     ? w3  : v;
        v = (i == j + 1) ? w2v : v;
        v = (i == j + 2) ? w1v : v;
        v = (i == j + 3) ? w0  : v;
        bj[j] = v;
    }
}

__device__ __forceinline__ void eval_g(float x, float g[NCH]) {
    float sl, bj[8];
    eval_gb(x, sl, bj);
    g[0] = sl;
#pragma unroll
    for (int j = 0; j < 8; ++j) g[j + 1] = bj[j];
}

// ---- prep: composed 5x5 kernel (f16 bases + f32 silu) and border-fold weights
// WV[uv][tap][ch] = sum_c rw[c,uv] * W1[c,tap,ch]
__global__ void ConvKAN_prep(const float* __restrict__ bw, const float* __restrict__ sw,
                             const float* __restrict__ ss, const float* __restrict__ rw,
                             float* __restrict__ ws) {
    __shared__ float W1s[NCONV * 81];
    __shared__ float WC[225];
    int t = threadIdx.x;
    for (int idx = t; idx < NCONV * 81; idx += 256) {
        int ci = idx / NCH;
        int ch = idx % NCH;
        W1s[idx] = (ch == 0) ? bw[ci] : sw[ci * 8 + (ch - 1)] * ss[ci];
    }
    __syncthreads();
    // Wc[(d*5+e)*9 + ch] = sum_c sum_{u,v} rw[c,u,v] * W1[c,ch,d-u,e-v]
    if (t < 225) {
        int de = t / NCH, ch = t % NCH;
        int d = de / 5, e = de % 5;
        float s = 0.0f;
        for (int c = 0; c < NCONV; ++c) {
            int ulo = d - 2 > 0 ? d - 2 : 0, uhi = d < 2 ? d : 2;
            int vlo = e - 2 > 0 ? e - 2 : 0, vhi = e < 2 ? e : 2;
            for (int u = ulo; u <= uhi; ++u)
                for (int v = vlo; v <= vhi; ++v) {
                    int i = (d - u) * 3 + (e - v);
                    s += rw[c * 9 + u * 3 + v] * W1s[(c * 9 + i) * NCH + ch];
                }
        }
        WC[t] = s;
    }
    // WV for border gather
    for (int idx = t; idx < 729; idx += 256) {
        int uv = idx / 81, rest = idx % 81;
        float s = 0.f;
        for (int c = 0; c < NCONV; ++c)
            s += rw[c * 9 + uv] * W1s[c * 81 + rest];
        ws[WOFF_WV + idx] = s;
    }
    __syncthreads();
    if (t < 25) {
        h8 hw;
#pragma unroll
        for (int j = 0; j < 8; ++j) hw[j] = (_Float16)WC[t * 9 + 1 + j];
        ((h8*)(ws + WOFF_WCH))[t] = hw;
        ws[WOFF_WCS + t] = WC[t * 9];
    }
}

// ---- main: unchanged (f16 bases in LDS, f16 weights, fdot2 hot loop)
__global__ __launch_bounds__(256) void ConvKAN_main(const float* __restrict__ x,
                                                    const float* __restrict__ wpack,
                                                    const float* __restrict__ wsl,
                                                    const float* __restrict__ rb,
                                                    float* __restrict__ out) {
    __shared__ h8 HB[NPOS];       // bases 0..7 as f16x8 (16B)
    __shared__ float SS[NPOS];    // silu (f32)
    int tid = threadIdx.x;
    int b = blockIdx.z;
    int y0 = blockIdx.y * TILE, x0 = blockIdx.x * TILE;
    const float* xb = x + (size_t)b * IMG_H * IMG_W;

    for (int i = tid; i < NPOS; i += 256) {
        int r = i / GDIM, c = i % GDIM;
        int gy = y0 + r - 2, gx = x0 + c - 2;
        float xv = (gy >= 0 && gy < IMG_H && gx >= 0 && gx < IMG_W) ? xb[gy * IMG_W + gx] : 0.0f;
        float sl, bj[8];
        eval_gb(xv, sl, bj);   // OOB -> g(0): matches zero-padded im2col semantics
        h8 hv;
#pragma unroll
        for (int j = 0; j < 8; ++j) hv[j] = (_Float16)bj[j];
        HB[i] = hv; SS[i] = sl;
    }
    __syncthreads();

    int tx = tid & 31;
    int ty = tid >> 5;          // 0..7
    int r0 = ty * 4;            // first output row (tile coords) of this thread
    float bias = rb[0];
    float acc[4] = {bias, bias, bias, bias};

#pragma unroll
    for (int R = 0; R < 8; ++R) {       // g rows r0+R cover rows needed by pixels p=0..3
#pragma unroll
        for (int e = 0; e < 5; ++e) {
            int pos = (r0 + R) * GDIM + tx + e;
            h8 hv = HB[pos]; float sl = SS[pos];
            h2 b0 = {hv[0], hv[1]}, b1 = {hv[2], hv[3]};
            h2 b2 = {hv[4], hv[5]}, b3 = {hv[6], hv[7]};
#pragma unroll
            for (int p = 0; p < 4; ++p) {
                int d = R - p;
                if (d < 0 || d > 4) continue;          // compile-time eliminated
                int t = d * 5 + e;
                const h2* wh = (const h2*)&wpack[t * 4];   // 8 f16 = 4 floats per tap
                float a0 = fmaf(sl, wsl[t], acc[p]);
                a0 = __builtin_amdgcn_fdot2(b0, wh[0], a0, false);
                a0 = __builtin_amdgcn_fdot2(b1, wh[1], a0, false);
                a0 = __builtin_amdgcn_fdot2(b2, wh[2], a0, false);
                a0 = __builtin_amdgcn_fdot2(b3, wh[3], a0, false);
                acc[p] = a0;
            }
        }
    }
    float* ob = out + ((size_t)b * IMG_H + y0) * IMG_W + x0;
#pragma unroll
    for (int p = 0; p < 4; ++p)
        ob[(r0 + p) * IMG_W + tx] = acc[p];
}

// ---- border correction v4: one thread per (border pixel, uv neighbor slot).
// 147k threads / 575 blocks: latency hidden by TLP; 9 INDEPENDENT x-loads
// hoisted ahead of eval chain; one atomicAdd per active thread (<=5/pixel).
__global__ __launch_bounds__(256) void ConvKAN_corr(const float* __restrict__ x,
        const float* __restrict__ wv, float* __restrict__ out) {
    __shared__ float WV[729];
    int tid = threadIdx.x;
    for (int idx = tid; idx < 729; idx += 256) WV[idx] = wv[idx];
    __syncthreads();

    int q = blockIdx.x * 256 + tid;
    if (q >= 9 * NPIX) return;
    int uv = q / NPIX;            // wave-uniform (except block-boundary waves)
    int pq = q % NPIX;
    int b = pq / NBORD, r = pq % NBORD;
    int y, xc;
    if (r < IMG_W)               { y = 0;             xc = r; }
    else if (r < 2 * IMG_W)      { y = IMG_H - 1;     xc = r - IMG_W; }
    else if (r < 2 * IMG_W + IMG_H - 2) { y = r - 2 * IMG_W + 1; xc = 0; }
    else                         { y = r - (2 * IMG_W + IMG_H - 2) + 1; xc = IMG_W - 1; }

    int du = uv / 3 - 1, dv = uv % 3 - 1;
    int fy = y + du, fx = xc + dv;
    if (fy >= 0 && fy < IMG_H && fx >= 0 && fx < IMG_W) return;  // inside: no correction

    const float* xb = x + (size_t)b * IMG_H * IMG_W;
    float xv[9];
#pragma unroll
    for (int tap = 0; tap < 9; ++tap) {         // independent loads, all in flight
        int gy = fy + tap / 3 - 1, gx = fx + tap % 3 - 1;
        xv[tap] = (gy >= 0 && gy < IMG_H && gx >= 0 && gx < IMG_W) ? xb[gy * IMG_W + gx] : 0.f;
    }
    const float* wvp = &WV[uv * 81];
    float corr = 0.f;
#pragma unroll
    for (int tap = 0; tap < 9; ++tap) {
        float g[NCH];
        eval_g(xv[tap], g);
#pragma unroll
        for (int ch = 0; ch < NCH; ++ch)
            corr = fmaf(wvp[tap * 9 + ch], g[ch], corr);
    }
    atomicAdd(&out[((size_t)b * IMG_H + y) * IMG_W + xc], -corr);
}

extern "C" void kernel_launch(void* const* d_in, const int* in_sizes, int n_in,
                              void* d_out, int out_size, void* d_ws, size_t ws_size,
                              hipStream_t stream) {
    const float* x  = (const float*)d_in[0];
    const float* bw = (const float*)d_in[1];
    const float* sw = (const float*)d_in[2];
    const float* ss = (const float*)d_in[3];
    const float* rw = (const float*)d_in[4];
    const float* rb = (const float*)d_in[5];
    float* out = (float*)d_out;
    float* ws  = (float*)d_ws;

    ConvKAN_prep<<<1, 256, 0, stream>>>(bw, sw, ss, rw, ws);
    ConvKAN_main<<<dim3(IMG_W / TILE, IMG_H / TILE, NBATCH), 256, 0, stream>>>(
        x, ws + WOFF_WCH, ws + WOFF_WCS, rb, out);
    int nthr = 9 * NPIX;                         // 147168
    ConvKAN_corr<<<(nthr + 255) / 256, 256, 0, stream>>>(x, ws + WOFF_WV, out);
}